// Round 3
// baseline (354.807 us; speedup 1.0000x reference)
//
#include <hip/hip_runtime.h>
#include <cstdint>
#include <cstddef>

typedef _Float16 half8  __attribute__((ext_vector_type(8)));
typedef float    f32x4  __attribute__((ext_vector_type(4)));

constexpr int Bc = 4, Tc = 4096, Hc = 16, NBc = 32, Dc = 1024, HIDc = 128;
constexpr int HN = Hc * NBc;      // 512
constexpr int BT = Bc * Tc;       // 16384

// ---------------------------------------------------------------------------
// split helper: 8 f32 -> f16 hi/lo (3-term split-f16 MFMA precision)
// ---------------------------------------------------------------------------
__device__ inline void split8(const float* __restrict__ p,
                              _Float16* __restrict__ dh,
                              _Float16* __restrict__ dl) {
  float4 a = *reinterpret_cast<const float4*>(p);
  float4 b = *reinterpret_cast<const float4*>(p + 4);
  float v[8] = {a.x, a.y, a.z, a.w, b.x, b.y, b.z, b.w};
  half8 hi, lo;
#pragma unroll
  for (int j = 0; j < 8; j++) {
    _Float16 h = (_Float16)v[j];
    hi[j] = h;
    lo[j] = (_Float16)(v[j] - (float)h);
  }
  *reinterpret_cast<half8*>(dh) = hi;
  *reinterpret_cast<half8*>(dl) = lo;
}

// ---------------------------------------------------------------------------
// Kernel: build transposed f16 hi/lo weights.
// ---------------------------------------------------------------------------
__global__ __launch_bounds__(256) void k_split_w(
    const float* __restrict__ mw1, const float* __restrict__ gw1,
    const float* __restrict__ mw2, const float* __restrict__ gw2,
    _Float16* __restrict__ W1Thi, _Float16* __restrict__ W1Tlo,
    _Float16* __restrict__ W2Thi, _Float16* __restrict__ W2Tlo) {
  unsigned i = blockIdx.x * 256u + threadIdx.x;
  if (i < 262144u) {                                   // W1T: n in [0,256), k in [0,1024)
    unsigned n = i >> 10, k = i & 1023u;
    float v = (n < 128u) ? mw1[k * 128u + n] : gw1[k * 128u + (n - 128u)];
    _Float16 h = (_Float16)v;
    W1Thi[i] = h;
    W1Tlo[i] = (_Float16)(v - (float)h);
  } else {                                             // W2T: j in [0,1024), k in [0,128)
    unsigned j2 = i - 262144u;
    unsigned n = j2 >> 7, k = j2 & 127u;
    float v = (n < 512u) ? mw2[k * 512u + n] : gw2[k * 512u + (n - 512u)];
    _Float16 h = (_Float16)v;
    W2Thi[j2] = h;
    W2Tlo[j2] = (_Float16)(v - (float)h);
  }
}

// ---------------------------------------------------------------------------
// GEMM1: h[16384][256] = gelu(X @ [mw1|gw1] + [mb1|gb1]); split-f16 MFMA.
// ---------------------------------------------------------------------------
__global__ __launch_bounds__(256) void k_gemm1(
    const float* __restrict__ X,
    const _Float16* __restrict__ Whi, const _Float16* __restrict__ Wlo,
    const float* __restrict__ mb1, const float* __restrict__ gb1,
    _Float16* __restrict__ Hhi, _Float16* __restrict__ Hlo) {
  __shared__ _Float16 sAh[128][40], sAl[128][40];   // +8 pad: 80B row stride
  __shared__ _Float16 sBh[64][40],  sBl[64][40];
  const int tid  = threadIdx.x;
  const int lane = tid & 63;
  const int w    = tid >> 6;
  const int wr   = w >> 1, wc = w & 1;
  const int rm   = blockIdx.x * 128;
  const int cn   = blockIdx.y * 64;
  const int lr   = lane & 15, kg = (lane >> 4) * 8;

  f32x4 acc[4][2] = {};

  for (int kt = 0; kt < 1024; kt += 32) {
#pragma unroll
    for (int j = 0; j < 2; j++) {
      int row = j * 64 + (tid >> 2);
      int k0  = (tid & 3) * 8;
      size_t g = (size_t)(rm + row) * 1024 + kt + k0;
      split8(X + g, &sAh[row][k0], &sAl[row][k0]);
    }
    {
      int n  = tid >> 2;
      int k0 = (tid & 3) * 8;
      size_t g = (size_t)(cn + n) * 1024 + kt + k0;
      *reinterpret_cast<uint4*>(&sBh[n][k0]) = *reinterpret_cast<const uint4*>(Whi + g);
      *reinterpret_cast<uint4*>(&sBl[n][k0]) = *reinterpret_cast<const uint4*>(Wlo + g);
    }
    __syncthreads();

    half8 ah[4], al[4], bh[2], bl[2];
#pragma unroll
    for (int m = 0; m < 4; m++) {
      ah[m] = *reinterpret_cast<const half8*>(&sAh[wr * 64 + m * 16 + lr][kg]);
      al[m] = *reinterpret_cast<const half8*>(&sAl[wr * 64 + m * 16 + lr][kg]);
    }
#pragma unroll
    for (int n = 0; n < 2; n++) {
      bh[n] = *reinterpret_cast<const half8*>(&sBh[wc * 32 + n * 16 + lr][kg]);
      bl[n] = *reinterpret_cast<const half8*>(&sBl[wc * 32 + n * 16 + lr][kg]);
    }
#pragma unroll
    for (int m = 0; m < 4; m++)
#pragma unroll
      for (int n = 0; n < 2; n++) {
        acc[m][n] = __builtin_amdgcn_mfma_f32_16x16x32_f16(ah[m], bh[n], acc[m][n], 0, 0, 0);
        acc[m][n] = __builtin_amdgcn_mfma_f32_16x16x32_f16(ah[m], bl[n], acc[m][n], 0, 0, 0);
        acc[m][n] = __builtin_amdgcn_mfma_f32_16x16x32_f16(al[m], bh[n], acc[m][n], 0, 0, 0);
      }
    __syncthreads();
  }

#pragma unroll
  for (int n = 0; n < 2; n++) {
    int colg = cn + wc * 32 + n * 16 + lr;
    float bias = (colg < 128) ? mb1[colg] : gb1[colg - 128];
#pragma unroll
    for (int m = 0; m < 4; m++) {
#pragma unroll
      for (int r = 0; r < 4; r++) {
        int rowg = rm + wr * 64 + m * 16 + (lane >> 4) * 4 + r;
        float v  = acc[m][n][r] + bias;
        float ge = 0.5f * v * (1.0f + erff(v * 0.70710678118654752f));
        _Float16 h = (_Float16)ge;
        Hhi[(size_t)rowg * 256 + colg] = h;
        Hlo[(size_t)rowg * 256 + colg] = (_Float16)(ge - (float)h);
      }
    }
  }
}

// ---------------------------------------------------------------------------
// GEMM2: logits[16384][1024]; cols<512: z = pi*tanh(.)  -> zbuf[row][512]
//                             cols>=512: g = sigmoid(.) -> gout[row][512]
// ---------------------------------------------------------------------------
__global__ __launch_bounds__(256) void k_gemm2(
    const _Float16* __restrict__ Hhi, const _Float16* __restrict__ Hlo,
    const _Float16* __restrict__ Whi, const _Float16* __restrict__ Wlo,
    const float* __restrict__ mb2, const float* __restrict__ gb2,
    float* __restrict__ zbuf, float* __restrict__ gout) {
  __shared__ _Float16 sAh[128][40], sAl[128][40];
  __shared__ _Float16 sBh[64][40],  sBl[64][40];
  const int tid  = threadIdx.x;
  const int lane = tid & 63;
  const int w    = tid >> 6;
  const int wr   = w >> 1, wc = w & 1;
  const int rm   = blockIdx.x * 128;
  const int cn   = blockIdx.y * 64;
  const int khead = (cn < 512) ? 0 : 128;
  const int lr   = lane & 15, kg = (lane >> 4) * 8;

  f32x4 acc[4][2] = {};

  for (int kt = 0; kt < 128; kt += 32) {
#pragma unroll
    for (int j = 0; j < 2; j++) {
      int row = j * 64 + (tid >> 2);
      int k0  = (tid & 3) * 8;
      size_t g = (size_t)(rm + row) * 256 + khead + kt + k0;
      *reinterpret_cast<uint4*>(&sAh[row][k0]) = *reinterpret_cast<const uint4*>(Hhi + g);
      *reinterpret_cast<uint4*>(&sAl[row][k0]) = *reinterpret_cast<const uint4*>(Hlo + g);
    }
    {
      int n  = tid >> 2;
      int k0 = (tid & 3) * 8;
      size_t g = (size_t)(cn + n) * 128 + kt + k0;
      *reinterpret_cast<uint4*>(&sBh[n][k0]) = *reinterpret_cast<const uint4*>(Whi + g);
      *reinterpret_cast<uint4*>(&sBl[n][k0]) = *reinterpret_cast<const uint4*>(Wlo + g);
    }
    __syncthreads();

    half8 ah[4], al[4], bh[2], bl[2];
#pragma unroll
    for (int m = 0; m < 4; m++) {
      ah[m] = *reinterpret_cast<const half8*>(&sAh[wr * 64 + m * 16 + lr][kg]);
      al[m] = *reinterpret_cast<const half8*>(&sAl[wr * 64 + m * 16 + lr][kg]);
    }
#pragma unroll
    for (int n = 0; n < 2; n++) {
      bh[n] = *reinterpret_cast<const half8*>(&sBh[wc * 32 + n * 16 + lr][kg]);
      bl[n] = *reinterpret_cast<const half8*>(&sBl[wc * 32 + n * 16 + lr][kg]);
    }
#pragma unroll
    for (int m = 0; m < 4; m++)
#pragma unroll
      for (int n = 0; n < 2; n++) {
        acc[m][n] = __builtin_amdgcn_mfma_f32_16x16x32_f16(ah[m], bh[n], acc[m][n], 0, 0, 0);
        acc[m][n] = __builtin_amdgcn_mfma_f32_16x16x32_f16(ah[m], bl[n], acc[m][n], 0, 0, 0);
        acc[m][n] = __builtin_amdgcn_mfma_f32_16x16x32_f16(al[m], bh[n], acc[m][n], 0, 0, 0);
      }
    __syncthreads();
  }

  const float PI = 3.14159265358979323846f;
#pragma unroll
  for (int n = 0; n < 2; n++) {
    int colg = cn + wc * 32 + n * 16 + lr;
    bool isz = (colg < 512);
    float bias = isz ? mb2[colg] : gb2[colg - 512];
#pragma unroll
    for (int m = 0; m < 4; m++) {
#pragma unroll
      for (int r = 0; r < 4; r++) {
        int rowg = rm + wr * 64 + m * 16 + (lane >> 4) * 4 + r;
        float v  = acc[m][n][r] + bias;
        if (isz) {
          zbuf[(size_t)rowg * 512 + colg] = PI * tanhf(v);
        } else {
          gout[(size_t)rowg * 512 + (colg - 512)] = 1.0f / (1.0f + expf(-v));
        }
      }
    }
  }
}

// ---------------------------------------------------------------------------
// Sigma recurrence as Mobius (LFT) parallel scan over T (as round 2).
// ---------------------------------------------------------------------------
__global__ __launch_bounds__(64) void k_mob1(
    const float* __restrict__ g, const float* __restrict__ logQ,
    const float* __restrict__ logR, float* __restrict__ Mbuf) {
  const int c  = blockIdx.x * 64 + threadIdx.x;   // channel 0..2047
  const int ts = blockIdx.y;                      // chunk 0..63
  const int b  = c >> 9, hn = c & 511;
  const float Q = expf(logQ[hn]);
  const float R = expf(logR[hn]);
  const unsigned base = (unsigned)b * (unsigned)(Tc * HN) + (unsigned)(ts * 64) * (unsigned)HN + (unsigned)hn;

  float ma = 1.f, mb = 0.f, mc = 0.f, md = 1.f;
  float gv[32];
#pragma unroll 1
  for (int ph = 0; ph < 2; ph++) {
#pragma unroll
    for (int j = 0; j < 32; j++) gv[j] = g[base + (unsigned)(ph * 32 + j) * 512u];
#pragma unroll
    for (int j = 0; j < 32; j++) {
      float re = R * __builtin_amdgcn_rcpf(gv[j] + 1e-4f);
      float t1 = __builtin_fmaf(Q, mc, ma);
      float t2 = __builtin_fmaf(Q, md, mb);
      ma = re * t1;
      mb = re * t2;
      mc = __builtin_fmaf(re, mc, t1);
      md = __builtin_fmaf(re, md, t2);
      if ((j & 3) == 3) {
        float r = __builtin_amdgcn_rcpf(md);
        ma *= r; mb *= r; mc *= r; md *= r;
      }
    }
  }
  f32x4 M; M[0] = ma; M[1] = mb; M[2] = mc; M[3] = md;
  reinterpret_cast<f32x4*>(Mbuf)[ts * 2048 + c] = M;
}

__global__ __launch_bounds__(64) void k_mob2(
    const float* __restrict__ Mbuf, const float* __restrict__ logS0,
    float* __restrict__ sstart) {
  const int c  = blockIdx.x * 64 + threadIdx.x;   // 0..2047
  const int hn = c & 511;
  float s = expf(logS0[hn]);
  const f32x4* M4 = reinterpret_cast<const f32x4*>(Mbuf);
  f32x4 ring[8];
#pragma unroll
  for (int i = 0; i < 8; i++) ring[i] = M4[i * 2048 + c];
#pragma unroll
  for (int ts = 0; ts < 64; ts++) {
    sstart[ts * 2048 + c] = s;
    f32x4 M = ring[ts & 7];
    if (ts + 8 < 64) ring[ts & 7] = M4[(ts + 8) * 2048 + c];
    s = (M[0] * s + M[1]) / (M[2] * s + M[3]);
  }
}

__global__ __launch_bounds__(64) void k_mob3(
    const float* __restrict__ g, const float* __restrict__ logQ,
    const float* __restrict__ logR, const float* __restrict__ sstart,
    float* __restrict__ Kbuf, float* __restrict__ osig) {
  const int c  = blockIdx.x * 64 + threadIdx.x;
  const int ts = blockIdx.y;
  const int b  = c >> 9, hn = c & 511;
  const float Q = expf(logQ[hn]);
  const float R = expf(logR[hn]);
  const unsigned base = (unsigned)b * (unsigned)(Tc * HN) + (unsigned)(ts * 64) * (unsigned)HN + (unsigned)hn;

  float s = sstart[ts * 2048 + c];
  float gv[32];
#pragma unroll 1
  for (int ph = 0; ph < 2; ph++) {
#pragma unroll
    for (int j = 0; j < 32; j++) gv[j] = g[base + (unsigned)(ph * 32 + j) * 512u];
#pragma unroll
    for (int j = 0; j < 32; j++) {
      const unsigned idx = base + (unsigned)(ph * 32 + j) * 512u;
      float re = R * __builtin_amdgcn_rcpf(gv[j] + 1e-4f);
      float sp = s + Q;
      float K  = sp * __builtin_amdgcn_rcpf(sp + re);
      s = K * re;
      Kbuf[idx] = K;        // Kbuf aliases out_theta ([b][t][hn] layout)
      osig[idx] = s;
    }
  }
}

// ---------------------------------------------------------------------------
// Serial theta scan. P=32 register prefetch ring (lookahead > HBM latency).
// Wrap arithmetic preserved BIT-EXACTLY from the passing round-1/2 kernels.
// Karr aliases oth (out_theta): K[idx] is read P steps before theta[idx] is
// stored to the same address by the same (channel-owning) thread -> safe.
// ---------------------------------------------------------------------------
__global__ __launch_bounds__(64) void k_scan_theta(
    const float* __restrict__ tp, const float* __restrict__ zarr,
    const float* __restrict__ Karr, float* __restrict__ oth) {
  const int c  = blockIdx.x * 64 + threadIdx.x;   // 0..2047
  const int b  = c >> 9;
  const int hn = c & 511;
  const unsigned base = (unsigned)b * (unsigned)(Tc * HN) + (unsigned)hn;

  float theta = 0.f, tprev = 0.f;

  constexpr float INV2PI = 0.15915494309189535f;
  constexpr float TWOPI  = 6.283185307179586f;
  constexpr int P = 32;

  float ptp[P], pz[P], pK[P];
#pragma unroll
  for (int i = 0; i < P; i++) {
    unsigned idx = base + (unsigned)i * 512u;
    ptp[i] = tp[idx];
    pz[i]  = zarr[idx];
    pK[i]  = Karr[idx];
  }

  auto dostep = [&](float tpv, float zv, float Kv, unsigned idx) {
    float inc = tpv - tprev; tprev = tpv;
    float thp = theta + inc;
    float d   = zv - thp;
    float nr  = rintf(d * INV2PI);
    float innov = __builtin_fmaf(-TWOPI, nr, d);
    theta = __builtin_fmaf(Kv, innov, thp);
    oth[idx] = theta;
  };

  for (int tb = 0; tb < Tc - P; tb += P) {
#pragma unroll
    for (int i = 0; i < P; i++) {
      const unsigned idx  = base + (unsigned)(tb + i) * 512u;
      const unsigned pidx = idx + (unsigned)P * 512u;
      float tpv = ptp[i], zv = pz[i], Kv = pK[i];
      ptp[i] = tp[pidx];
      pz[i]  = zarr[pidx];
      pK[i]  = Karr[pidx];
      dostep(tpv, zv, Kv, idx);
    }
  }
#pragma unroll
  for (int i = 0; i < P; i++) {
    const unsigned idx = base + (unsigned)(Tc - P + i) * 512u;
    dostep(ptp[i], pz[i], pK[i], idx);
  }
}

// ---------------------------------------------------------------------------
extern "C" void kernel_launch(void* const* d_in, const int* in_sizes, int n_in,
                              void* d_out, int out_size, void* d_ws, size_t ws_size,
                              hipStream_t stream) {
  const float* theta_path = (const float*)d_in[0];
  const float* X     = (const float*)d_in[1];
  const float* mw1   = (const float*)d_in[2];
  const float* mb1   = (const float*)d_in[3];
  const float* mw2   = (const float*)d_in[4];
  const float* mb2   = (const float*)d_in[5];
  const float* gw1   = (const float*)d_in[6];
  const float* gb1   = (const float*)d_in[7];
  const float* gw2   = (const float*)d_in[8];
  const float* gb2   = (const float*)d_in[9];
  const float* logQ  = (const float*)d_in[10];
  const float* logR  = (const float*)d_in[11];
  const float* logS0 = (const float*)d_in[12];

  const size_t NOUT = (size_t)BT * HN;       // 8,388,608 per output tensor
  float* out_theta = (float*)d_out;
  float* out_sigma = out_theta + NOUT;
  float* out_g     = out_theta + 2 * NOUT;

  // K buffer aliases out_theta (identical [b][t][hn] layout); scan reads
  // K[idx] 32 steps before storing theta[idx] to the same address.
  float* Kbuf = out_theta;

  char* ws = (char*)d_ws;
  _Float16* W1Thi = (_Float16*)(ws);                               // 512 KB
  _Float16* W1Tlo = (_Float16*)(ws + (512u << 10));                // 512 KB
  _Float16* W2Thi = (_Float16*)(ws + (1024u << 10));               // 256 KB
  _Float16* W2Tlo = (_Float16*)(ws + (1280u << 10));               // 256 KB
  _Float16* Hhi   = (_Float16*)(ws + (1536u << 10));               // 8 MB
  _Float16* Hlo   = (_Float16*)(ws + (1536u << 10) + (8u << 20));  // 8 MB
  float*    zbuf  = (float*)  (ws + (1536u << 10) + (16u << 20));  // 32 MB
  float*    Mbuf  = (float*)  (ws + (1536u << 10) + (48u << 20));  // 2 MB
  float*    sst   = (float*)  (ws + (1536u << 10) + (50u << 20));  // 512 KB
  // total ws use ~52 MB (same footprint as the proven round-2 layout)

  k_split_w<<<1536, 256, 0, stream>>>(mw1, gw1, mw2, gw2, W1Thi, W1Tlo, W2Thi, W2Tlo);
  k_gemm1<<<dim3(128, 4), 256, 0, stream>>>(X, W1Thi, W1Tlo, mb1, gb1, Hhi, Hlo);
  k_gemm2<<<dim3(128, 16), 256, 0, stream>>>(Hhi, Hlo, W2Thi, W2Tlo, mb2, gb2, zbuf, out_g);
  k_mob1<<<dim3(32, 64), 64, 0, stream>>>(out_g, logQ, logR, Mbuf);
  k_mob2<<<32, 64, 0, stream>>>(Mbuf, logS0, sst);
  k_mob3<<<dim3(32, 64), 64, 0, stream>>>(out_g, logQ, logR, sst, Kbuf, out_sigma);
  k_scan_theta<<<32, 64, 0, stream>>>(theta_path, zbuf, Kbuf, out_theta);
}

// Round 4
// 235.645 us; speedup vs baseline: 1.5057x; 1.5057x over previous
//
#include <hip/hip_runtime.h>
#include <cstdint>
#include <cstddef>

typedef _Float16 half8  __attribute__((ext_vector_type(8)));
typedef float    f32x4  __attribute__((ext_vector_type(4)));

constexpr int Bc = 4, Tc = 4096, Hc = 16, NBc = 32, Dc = 1024, HIDc = 128;
constexpr int HN = Hc * NBc;      // 512
constexpr int BT = Bc * Tc;       // 16384

// ---------------------------------------------------------------------------
// split helper: 8 f32 -> f16 hi/lo (3-term split-f16 MFMA precision)
// ---------------------------------------------------------------------------
__device__ inline void split8(const float* __restrict__ p,
                              _Float16* __restrict__ dh,
                              _Float16* __restrict__ dl) {
  float4 a = *reinterpret_cast<const float4*>(p);
  float4 b = *reinterpret_cast<const float4*>(p + 4);
  float v[8] = {a.x, a.y, a.z, a.w, b.x, b.y, b.z, b.w};
  half8 hi, lo;
#pragma unroll
  for (int j = 0; j < 8; j++) {
    _Float16 h = (_Float16)v[j];
    hi[j] = h;
    lo[j] = (_Float16)(v[j] - (float)h);
  }
  *reinterpret_cast<half8*>(dh) = hi;
  *reinterpret_cast<half8*>(dl) = lo;
}

// ---------------------------------------------------------------------------
// Kernel: build transposed f16 hi/lo weights.
// ---------------------------------------------------------------------------
__global__ __launch_bounds__(256) void k_split_w(
    const float* __restrict__ mw1, const float* __restrict__ gw1,
    const float* __restrict__ mw2, const float* __restrict__ gw2,
    _Float16* __restrict__ W1Thi, _Float16* __restrict__ W1Tlo,
    _Float16* __restrict__ W2Thi, _Float16* __restrict__ W2Tlo) {
  unsigned i = blockIdx.x * 256u + threadIdx.x;
  if (i < 262144u) {                                   // W1T: n in [0,256), k in [0,1024)
    unsigned n = i >> 10, k = i & 1023u;
    float v = (n < 128u) ? mw1[k * 128u + n] : gw1[k * 128u + (n - 128u)];
    _Float16 h = (_Float16)v;
    W1Thi[i] = h;
    W1Tlo[i] = (_Float16)(v - (float)h);
  } else {                                             // W2T: j in [0,1024), k in [0,128)
    unsigned j2 = i - 262144u;
    unsigned n = j2 >> 7, k = j2 & 127u;
    float v = (n < 512u) ? mw2[k * 512u + n] : gw2[k * 512u + (n - 512u)];
    _Float16 h = (_Float16)v;
    W2Thi[j2] = h;
    W2Tlo[j2] = (_Float16)(v - (float)h);
  }
}

// ---------------------------------------------------------------------------
// GEMM1: h[16384][256] = gelu(X @ [mw1|gw1] + [mb1|gb1]); split-f16 MFMA.
// ---------------------------------------------------------------------------
__global__ __launch_bounds__(256) void k_gemm1(
    const float* __restrict__ X,
    const _Float16* __restrict__ Whi, const _Float16* __restrict__ Wlo,
    const float* __restrict__ mb1, const float* __restrict__ gb1,
    _Float16* __restrict__ Hhi, _Float16* __restrict__ Hlo) {
  __shared__ _Float16 sAh[128][40], sAl[128][40];   // +8 pad: 80B row stride
  __shared__ _Float16 sBh[64][40],  sBl[64][40];
  const int tid  = threadIdx.x;
  const int lane = tid & 63;
  const int w    = tid >> 6;
  const int wr   = w >> 1, wc = w & 1;
  const int rm   = blockIdx.x * 128;
  const int cn   = blockIdx.y * 64;
  const int lr   = lane & 15, kg = (lane >> 4) * 8;

  f32x4 acc[4][2] = {};

  for (int kt = 0; kt < 1024; kt += 32) {
#pragma unroll
    for (int j = 0; j < 2; j++) {
      int row = j * 64 + (tid >> 2);
      int k0  = (tid & 3) * 8;
      size_t g = (size_t)(rm + row) * 1024 + kt + k0;
      split8(X + g, &sAh[row][k0], &sAl[row][k0]);
    }
    {
      int n  = tid >> 2;
      int k0 = (tid & 3) * 8;
      size_t g = (size_t)(cn + n) * 1024 + kt + k0;
      *reinterpret_cast<uint4*>(&sBh[n][k0]) = *reinterpret_cast<const uint4*>(Whi + g);
      *reinterpret_cast<uint4*>(&sBl[n][k0]) = *reinterpret_cast<const uint4*>(Wlo + g);
    }
    __syncthreads();

    half8 ah[4], al[4], bh[2], bl[2];
#pragma unroll
    for (int m = 0; m < 4; m++) {
      ah[m] = *reinterpret_cast<const half8*>(&sAh[wr * 64 + m * 16 + lr][kg]);
      al[m] = *reinterpret_cast<const half8*>(&sAl[wr * 64 + m * 16 + lr][kg]);
    }
#pragma unroll
    for (int n = 0; n < 2; n++) {
      bh[n] = *reinterpret_cast<const half8*>(&sBh[wc * 32 + n * 16 + lr][kg]);
      bl[n] = *reinterpret_cast<const half8*>(&sBl[wc * 32 + n * 16 + lr][kg]);
    }
#pragma unroll
    for (int m = 0; m < 4; m++)
#pragma unroll
      for (int n = 0; n < 2; n++) {
        acc[m][n] = __builtin_amdgcn_mfma_f32_16x16x32_f16(ah[m], bh[n], acc[m][n], 0, 0, 0);
        acc[m][n] = __builtin_amdgcn_mfma_f32_16x16x32_f16(ah[m], bl[n], acc[m][n], 0, 0, 0);
        acc[m][n] = __builtin_amdgcn_mfma_f32_16x16x32_f16(al[m], bh[n], acc[m][n], 0, 0, 0);
      }
    __syncthreads();
  }

#pragma unroll
  for (int n = 0; n < 2; n++) {
    int colg = cn + wc * 32 + n * 16 + lr;
    float bias = (colg < 128) ? mb1[colg] : gb1[colg - 128];
#pragma unroll
    for (int m = 0; m < 4; m++) {
#pragma unroll
      for (int r = 0; r < 4; r++) {
        int rowg = rm + wr * 64 + m * 16 + (lane >> 4) * 4 + r;
        float v  = acc[m][n][r] + bias;
        float ge = 0.5f * v * (1.0f + erff(v * 0.70710678118654752f));
        _Float16 h = (_Float16)ge;
        Hhi[(size_t)rowg * 256 + colg] = h;
        Hlo[(size_t)rowg * 256 + colg] = (_Float16)(ge - (float)h);
      }
    }
  }
}

// ---------------------------------------------------------------------------
// GEMM2: logits[16384][1024]; cols<512: z = pi*tanh(.)  -> zbuf[row][512]
//                             cols>=512: g = sigmoid(.) -> gout[row][512]
// ---------------------------------------------------------------------------
__global__ __launch_bounds__(256) void k_gemm2(
    const _Float16* __restrict__ Hhi, const _Float16* __restrict__ Hlo,
    const _Float16* __restrict__ Whi, const _Float16* __restrict__ Wlo,
    const float* __restrict__ mb2, const float* __restrict__ gb2,
    float* __restrict__ zbuf, float* __restrict__ gout) {
  __shared__ _Float16 sAh[128][40], sAl[128][40];
  __shared__ _Float16 sBh[64][40],  sBl[64][40];
  const int tid  = threadIdx.x;
  const int lane = tid & 63;
  const int w    = tid >> 6;
  const int wr   = w >> 1, wc = w & 1;
  const int rm   = blockIdx.x * 128;
  const int cn   = blockIdx.y * 64;
  const int khead = (cn < 512) ? 0 : 128;
  const int lr   = lane & 15, kg = (lane >> 4) * 8;

  f32x4 acc[4][2] = {};

  for (int kt = 0; kt < 128; kt += 32) {
#pragma unroll
    for (int j = 0; j < 2; j++) {
      int row = j * 64 + (tid >> 2);
      int k0  = (tid & 3) * 8;
      size_t g = (size_t)(rm + row) * 256 + khead + kt + k0;
      *reinterpret_cast<uint4*>(&sAh[row][k0]) = *reinterpret_cast<const uint4*>(Hhi + g);
      *reinterpret_cast<uint4*>(&sAl[row][k0]) = *reinterpret_cast<const uint4*>(Hlo + g);
    }
    {
      int n  = tid >> 2;
      int k0 = (tid & 3) * 8;
      size_t g = (size_t)(cn + n) * 128 + kt + k0;
      *reinterpret_cast<uint4*>(&sBh[n][k0]) = *reinterpret_cast<const uint4*>(Whi + g);
      *reinterpret_cast<uint4*>(&sBl[n][k0]) = *reinterpret_cast<const uint4*>(Wlo + g);
    }
    __syncthreads();

    half8 ah[4], al[4], bh[2], bl[2];
#pragma unroll
    for (int m = 0; m < 4; m++) {
      ah[m] = *reinterpret_cast<const half8*>(&sAh[wr * 64 + m * 16 + lr][kg]);
      al[m] = *reinterpret_cast<const half8*>(&sAl[wr * 64 + m * 16 + lr][kg]);
    }
#pragma unroll
    for (int n = 0; n < 2; n++) {
      bh[n] = *reinterpret_cast<const half8*>(&sBh[wc * 32 + n * 16 + lr][kg]);
      bl[n] = *reinterpret_cast<const half8*>(&sBl[wc * 32 + n * 16 + lr][kg]);
    }
#pragma unroll
    for (int m = 0; m < 4; m++)
#pragma unroll
      for (int n = 0; n < 2; n++) {
        acc[m][n] = __builtin_amdgcn_mfma_f32_16x16x32_f16(ah[m], bh[n], acc[m][n], 0, 0, 0);
        acc[m][n] = __builtin_amdgcn_mfma_f32_16x16x32_f16(ah[m], bl[n], acc[m][n], 0, 0, 0);
        acc[m][n] = __builtin_amdgcn_mfma_f32_16x16x32_f16(al[m], bh[n], acc[m][n], 0, 0, 0);
      }
    __syncthreads();
  }

  const float PI = 3.14159265358979323846f;
#pragma unroll
  for (int n = 0; n < 2; n++) {
    int colg = cn + wc * 32 + n * 16 + lr;
    bool isz = (colg < 512);
    float bias = isz ? mb2[colg] : gb2[colg - 512];
#pragma unroll
    for (int m = 0; m < 4; m++) {
#pragma unroll
      for (int r = 0; r < 4; r++) {
        int rowg = rm + wr * 64 + m * 16 + (lane >> 4) * 4 + r;
        float v  = acc[m][n][r] + bias;
        if (isz) {
          zbuf[(size_t)rowg * 512 + colg] = PI * tanhf(v);
        } else {
          gout[(size_t)rowg * 512 + (colg - 512)] = 1.0f / (1.0f + expf(-v));
        }
      }
    }
  }
}

// ---------------------------------------------------------------------------
// Sigma recurrence as Mobius (LFT) parallel scan over T (unchanged).
// ---------------------------------------------------------------------------
__global__ __launch_bounds__(64) void k_mob1(
    const float* __restrict__ g, const float* __restrict__ logQ,
    const float* __restrict__ logR, float* __restrict__ Mbuf) {
  const int c  = blockIdx.x * 64 + threadIdx.x;   // channel 0..2047
  const int ts = blockIdx.y;                      // chunk 0..63
  const int b  = c >> 9, hn = c & 511;
  const float Q = expf(logQ[hn]);
  const float R = expf(logR[hn]);
  const unsigned base = (unsigned)b * (unsigned)(Tc * HN) + (unsigned)(ts * 64) * (unsigned)HN + (unsigned)hn;

  float ma = 1.f, mb = 0.f, mc = 0.f, md = 1.f;
  float gv[32];
#pragma unroll 1
  for (int ph = 0; ph < 2; ph++) {
#pragma unroll
    for (int j = 0; j < 32; j++) gv[j] = g[base + (unsigned)(ph * 32 + j) * 512u];
#pragma unroll
    for (int j = 0; j < 32; j++) {
      float re = R * __builtin_amdgcn_rcpf(gv[j] + 1e-4f);
      float t1 = __builtin_fmaf(Q, mc, ma);
      float t2 = __builtin_fmaf(Q, md, mb);
      ma = re * t1;
      mb = re * t2;
      mc = __builtin_fmaf(re, mc, t1);
      md = __builtin_fmaf(re, md, t2);
      if ((j & 3) == 3) {
        float r = __builtin_amdgcn_rcpf(md);
        ma *= r; mb *= r; mc *= r; md *= r;
      }
    }
  }
  f32x4 M; M[0] = ma; M[1] = mb; M[2] = mc; M[3] = md;
  reinterpret_cast<f32x4*>(Mbuf)[ts * 2048 + c] = M;
}

__global__ __launch_bounds__(64) void k_mob2(
    const float* __restrict__ Mbuf, const float* __restrict__ logS0,
    float* __restrict__ sstart) {
  const int c  = blockIdx.x * 64 + threadIdx.x;   // 0..2047
  const int hn = c & 511;
  float s = expf(logS0[hn]);
  const f32x4* M4 = reinterpret_cast<const f32x4*>(Mbuf);
  f32x4 ring[8];
#pragma unroll
  for (int i = 0; i < 8; i++) ring[i] = M4[i * 2048 + c];
#pragma unroll
  for (int ts = 0; ts < 64; ts++) {
    sstart[ts * 2048 + c] = s;
    f32x4 M = ring[ts & 7];
    if (ts + 8 < 64) ring[ts & 7] = M4[(ts + 8) * 2048 + c];
    s = (M[0] * s + M[1]) / (M[2] * s + M[3]);
  }
}

__global__ __launch_bounds__(64) void k_mob3(
    const float* __restrict__ g, const float* __restrict__ logQ,
    const float* __restrict__ logR, const float* __restrict__ sstart,
    float* __restrict__ Kbuf, float* __restrict__ osig) {
  const int c  = blockIdx.x * 64 + threadIdx.x;
  const int ts = blockIdx.y;
  const int b  = c >> 9, hn = c & 511;
  const float Q = expf(logQ[hn]);
  const float R = expf(logR[hn]);
  const unsigned base = (unsigned)b * (unsigned)(Tc * HN) + (unsigned)(ts * 64) * (unsigned)HN + (unsigned)hn;

  float s = sstart[ts * 2048 + c];
  float gv[32];
#pragma unroll 1
  for (int ph = 0; ph < 2; ph++) {
#pragma unroll
    for (int j = 0; j < 32; j++) gv[j] = g[base + (unsigned)(ph * 32 + j) * 512u];
#pragma unroll
    for (int j = 0; j < 32; j++) {
      const unsigned idx = base + (unsigned)(ph * 32 + j) * 512u;
      float re = R * __builtin_amdgcn_rcpf(gv[j] + 1e-4f);
      float sp = s + Q;
      float K  = sp * __builtin_amdgcn_rcpf(sp + re);
      s = K * re;
      Kbuf[idx] = K;        // Kbuf aliases out_theta ([b][t][hn] layout)
      osig[idx] = s;
    }
  }
}

// ---------------------------------------------------------------------------
// Serial theta scan — producer/consumer wave specialization.
// Block = 448 thr (7 waves) per 64 channels. Wave 0: serial compute from LDS.
// Waves 1-6: stage chunk k+1 of {tp, z, K} (64 steps x 64 ch x 4B each)
// into double-buffered LDS while wave 0 computes chunk k. One barrier/chunk.
// Theta arithmetic is BIT-IDENTICAL to the passing round-2 kernel.
// Karr aliases oth: loaders read K[chunk k+1] strictly before wave 0 stores
// theta[chunk k+1] (barrier-ordered, disjoint t-ranges per phase) -> safe.
// ---------------------------------------------------------------------------
__global__ __launch_bounds__(448) void k_scan_theta(
    const float* __restrict__ tp, const float* __restrict__ zarr,
    const float* __restrict__ Karr, float* __restrict__ oth) {
  __shared__ float sbuf[2][3][64][64];   // [dbuf][stream][t][ch] = 96 KB
  const int tid  = threadIdx.x;
  const int lane = tid & 63;
  const int wv   = tid >> 6;            // 0..6
  const int c    = blockIdx.x * 64 + lane;
  const int b    = c >> 9;
  const int hn   = c & 511;
  const unsigned base = (unsigned)b * (unsigned)(Tc * HN) + (unsigned)hn;

  constexpr float INV2PI = 0.15915494309189535f;
  constexpr float TWOPI  = 6.283185307179586f;

  // loader role setup (wave-uniform)
  const int s = (wv - 1) >> 1;          // 0:tp 1:z 2:K
  const int h = (wv - 1) & 1;           // half of the 64-step chunk
  const float* src = (s == 0) ? tp : (s == 1) ? zarr : Karr;

  auto load_chunk = [&](int k) {
    float r[32];
    const unsigned tb = (unsigned)(k * 64 + h * 32);
#pragma unroll
    for (int j = 0; j < 32; j++) r[j] = src[base + (tb + (unsigned)j) * 512u];
#pragma unroll
    for (int j = 0; j < 32; j++) sbuf[k & 1][s][h * 32 + j][lane] = r[j];
  };

  float theta = 0.f, tprev = 0.f;

  if (wv >= 1) load_chunk(0);
  __syncthreads();

#pragma unroll 1
  for (int k = 0; k < 64; k++) {
    if (wv == 0) {
      // compute chunk k from LDS with P=8 register ring
      float rtp[8], rz[8], rK[8];
#pragma unroll
      for (int i = 0; i < 8; i++) {
        rtp[i] = sbuf[k & 1][0][i][lane];
        rz[i]  = sbuf[k & 1][1][i][lane];
        rK[i]  = sbuf[k & 1][2][i][lane];
      }
#pragma unroll
      for (int j = 0; j < 64; j++) {
        float tpv = rtp[j & 7], zv = rz[j & 7], Kv = rK[j & 7];
        if (j + 8 < 64) {
          rtp[j & 7] = sbuf[k & 1][0][j + 8][lane];
          rz[j & 7]  = sbuf[k & 1][1][j + 8][lane];
          rK[j & 7]  = sbuf[k & 1][2][j + 8][lane];
        }
        float inc = tpv - tprev; tprev = tpv;
        float thp = theta + inc;
        float d   = zv - thp;
        float nr  = rintf(d * INV2PI);
        float innov = __builtin_fmaf(-TWOPI, nr, d);
        theta = __builtin_fmaf(Kv, innov, thp);
        oth[base + (unsigned)(k * 64 + j) * 512u] = theta;
      }
    } else if (k + 1 < 64) {
      load_chunk(k + 1);
    }
    __syncthreads();
  }
}

// ---------------------------------------------------------------------------
extern "C" void kernel_launch(void* const* d_in, const int* in_sizes, int n_in,
                              void* d_out, int out_size, void* d_ws, size_t ws_size,
                              hipStream_t stream) {
  const float* theta_path = (const float*)d_in[0];
  const float* X     = (const float*)d_in[1];
  const float* mw1   = (const float*)d_in[2];
  const float* mb1   = (const float*)d_in[3];
  const float* mw2   = (const float*)d_in[4];
  const float* mb2   = (const float*)d_in[5];
  const float* gw1   = (const float*)d_in[6];
  const float* gb1   = (const float*)d_in[7];
  const float* gw2   = (const float*)d_in[8];
  const float* gb2   = (const float*)d_in[9];
  const float* logQ  = (const float*)d_in[10];
  const float* logR  = (const float*)d_in[11];
  const float* logS0 = (const float*)d_in[12];

  const size_t NOUT = (size_t)BT * HN;       // 8,388,608 per output tensor
  float* out_theta = (float*)d_out;
  float* out_sigma = out_theta + NOUT;
  float* out_g     = out_theta + 2 * NOUT;

  // K buffer aliases out_theta (identical [b][t][hn] layout); the scan's
  // loader waves read K[t] strictly before theta[t] is stored (barrier order).
  float* Kbuf = out_theta;

  char* ws = (char*)d_ws;
  _Float16* W1Thi = (_Float16*)(ws);                               // 512 KB
  _Float16* W1Tlo = (_Float16*)(ws + (512u << 10));                // 512 KB
  _Float16* W2Thi = (_Float16*)(ws + (1024u << 10));               // 256 KB
  _Float16* W2Tlo = (_Float16*)(ws + (1280u << 10));               // 256 KB
  _Float16* Hhi   = (_Float16*)(ws + (1536u << 10));               // 8 MB
  _Float16* Hlo   = (_Float16*)(ws + (1536u << 10) + (8u << 20));  // 8 MB
  float*    zbuf  = (float*)  (ws + (1536u << 10) + (16u << 20));  // 32 MB
  float*    Mbuf  = (float*)  (ws + (1536u << 10) + (48u << 20));  // 2 MB
  float*    sst   = (float*)  (ws + (1536u << 10) + (50u << 20));  // 512 KB
  // total ws use ~52 MB

  k_split_w<<<1536, 256, 0, stream>>>(mw1, gw1, mw2, gw2, W1Thi, W1Tlo, W2Thi, W2Tlo);
  k_gemm1<<<dim3(128, 4), 256, 0, stream>>>(X, W1Thi, W1Tlo, mb1, gb1, Hhi, Hlo);
  k_gemm2<<<dim3(128, 16), 256, 0, stream>>>(Hhi, Hlo, W2Thi, W2Tlo, mb2, gb2, zbuf, out_g);
  k_mob1<<<dim3(32, 64), 64, 0, stream>>>(out_g, logQ, logR, Mbuf);
  k_mob2<<<32, 64, 0, stream>>>(Mbuf, logS0, sst);
  k_mob3<<<dim3(32, 64), 64, 0, stream>>>(out_g, logQ, logR, sst, Kbuf, out_sigma);
  k_scan_theta<<<32, 448, 0, stream>>>(theta_path, zbuf, Kbuf, out_theta);
}

// Round 5
// 221.604 us; speedup vs baseline: 1.6011x; 1.0634x over previous
//
#include <hip/hip_runtime.h>
#include <cstdint>
#include <cstddef>

typedef _Float16 half8  __attribute__((ext_vector_type(8)));
typedef float    f32x4  __attribute__((ext_vector_type(4)));

constexpr int Bc = 4, Tc = 4096, Hc = 16, NBc = 32, Dc = 1024, HIDc = 128;
constexpr int HN = Hc * NBc;      // 512
constexpr int BT = Bc * Tc;       // 16384

// ---------------------------------------------------------------------------
// split helper: 8 f32 -> f16 hi/lo (3-term split-f16 MFMA precision)
// ---------------------------------------------------------------------------
__device__ inline void split8(const float* __restrict__ p,
                              _Float16* __restrict__ dh,
                              _Float16* __restrict__ dl) {
  float4 a = *reinterpret_cast<const float4*>(p);
  float4 b = *reinterpret_cast<const float4*>(p + 4);
  float v[8] = {a.x, a.y, a.z, a.w, b.x, b.y, b.z, b.w};
  half8 hi, lo;
#pragma unroll
  for (int j = 0; j < 8; j++) {
    _Float16 h = (_Float16)v[j];
    hi[j] = h;
    lo[j] = (_Float16)(v[j] - (float)h);
  }
  *reinterpret_cast<half8*>(dh) = hi;
  *reinterpret_cast<half8*>(dl) = lo;
}

// ---------------------------------------------------------------------------
// Kernel: build transposed f16 hi/lo weights.
// ---------------------------------------------------------------------------
__global__ __launch_bounds__(256) void k_split_w(
    const float* __restrict__ mw1, const float* __restrict__ gw1,
    const float* __restrict__ mw2, const float* __restrict__ gw2,
    _Float16* __restrict__ W1Thi, _Float16* __restrict__ W1Tlo,
    _Float16* __restrict__ W2Thi, _Float16* __restrict__ W2Tlo) {
  unsigned i = blockIdx.x * 256u + threadIdx.x;
  if (i < 262144u) {                                   // W1T: n in [0,256), k in [0,1024)
    unsigned n = i >> 10, k = i & 1023u;
    float v = (n < 128u) ? mw1[k * 128u + n] : gw1[k * 128u + (n - 128u)];
    _Float16 h = (_Float16)v;
    W1Thi[i] = h;
    W1Tlo[i] = (_Float16)(v - (float)h);
  } else {                                             // W2T: j in [0,1024), k in [0,128)
    unsigned j2 = i - 262144u;
    unsigned n = j2 >> 7, k = j2 & 127u;
    float v = (n < 512u) ? mw2[k * 512u + n] : gw2[k * 512u + (n - 512u)];
    _Float16 h = (_Float16)v;
    W2Thi[j2] = h;
    W2Tlo[j2] = (_Float16)(v - (float)h);
  }
}

// ---------------------------------------------------------------------------
// GEMM1: h[16384][256] = gelu(X @ [mw1|gw1] + [mb1|gb1]); split-f16 MFMA.
// ---------------------------------------------------------------------------
__global__ __launch_bounds__(256) void k_gemm1(
    const float* __restrict__ X,
    const _Float16* __restrict__ Whi, const _Float16* __restrict__ Wlo,
    const float* __restrict__ mb1, const float* __restrict__ gb1,
    _Float16* __restrict__ Hhi, _Float16* __restrict__ Hlo) {
  __shared__ _Float16 sAh[128][40], sAl[128][40];   // +8 pad: 80B row stride
  __shared__ _Float16 sBh[64][40],  sBl[64][40];
  const int tid  = threadIdx.x;
  const int lane = tid & 63;
  const int w    = tid >> 6;
  const int wr   = w >> 1, wc = w & 1;
  const int rm   = blockIdx.x * 128;
  const int cn   = blockIdx.y * 64;
  const int lr   = lane & 15, kg = (lane >> 4) * 8;

  f32x4 acc[4][2] = {};

  for (int kt = 0; kt < 1024; kt += 32) {
#pragma unroll
    for (int j = 0; j < 2; j++) {
      int row = j * 64 + (tid >> 2);
      int k0  = (tid & 3) * 8;
      size_t g = (size_t)(rm + row) * 1024 + kt + k0;
      split8(X + g, &sAh[row][k0], &sAl[row][k0]);
    }
    {
      int n  = tid >> 2;
      int k0 = (tid & 3) * 8;
      size_t g = (size_t)(cn + n) * 1024 + kt + k0;
      *reinterpret_cast<uint4*>(&sBh[n][k0]) = *reinterpret_cast<const uint4*>(Whi + g);
      *reinterpret_cast<uint4*>(&sBl[n][k0]) = *reinterpret_cast<const uint4*>(Wlo + g);
    }
    __syncthreads();

    half8 ah[4], al[4], bh[2], bl[2];
#pragma unroll
    for (int m = 0; m < 4; m++) {
      ah[m] = *reinterpret_cast<const half8*>(&sAh[wr * 64 + m * 16 + lr][kg]);
      al[m] = *reinterpret_cast<const half8*>(&sAl[wr * 64 + m * 16 + lr][kg]);
    }
#pragma unroll
    for (int n = 0; n < 2; n++) {
      bh[n] = *reinterpret_cast<const half8*>(&sBh[wc * 32 + n * 16 + lr][kg]);
      bl[n] = *reinterpret_cast<const half8*>(&sBl[wc * 32 + n * 16 + lr][kg]);
    }
#pragma unroll
    for (int m = 0; m < 4; m++)
#pragma unroll
      for (int n = 0; n < 2; n++) {
        acc[m][n] = __builtin_amdgcn_mfma_f32_16x16x32_f16(ah[m], bh[n], acc[m][n], 0, 0, 0);
        acc[m][n] = __builtin_amdgcn_mfma_f32_16x16x32_f16(ah[m], bl[n], acc[m][n], 0, 0, 0);
        acc[m][n] = __builtin_amdgcn_mfma_f32_16x16x32_f16(al[m], bh[n], acc[m][n], 0, 0, 0);
      }
    __syncthreads();
  }

#pragma unroll
  for (int n = 0; n < 2; n++) {
    int colg = cn + wc * 32 + n * 16 + lr;
    float bias = (colg < 128) ? mb1[colg] : gb1[colg - 128];
#pragma unroll
    for (int m = 0; m < 4; m++) {
#pragma unroll
      for (int r = 0; r < 4; r++) {
        int rowg = rm + wr * 64 + m * 16 + (lane >> 4) * 4 + r;
        float v  = acc[m][n][r] + bias;
        float ge = 0.5f * v * (1.0f + erff(v * 0.70710678118654752f));
        _Float16 h = (_Float16)ge;
        Hhi[(size_t)rowg * 256 + colg] = h;
        Hlo[(size_t)rowg * 256 + colg] = (_Float16)(ge - (float)h);
      }
    }
  }
}

// ---------------------------------------------------------------------------
// GEMM2: logits[16384][1024]; cols<512: z = pi*tanh(.)  -> zbuf[row][512]
//                             cols>=512: g = sigmoid(.) -> gout[row][512]
// ---------------------------------------------------------------------------
__global__ __launch_bounds__(256) void k_gemm2(
    const _Float16* __restrict__ Hhi, const _Float16* __restrict__ Hlo,
    const _Float16* __restrict__ Whi, const _Float16* __restrict__ Wlo,
    const float* __restrict__ mb2, const float* __restrict__ gb2,
    float* __restrict__ zbuf, float* __restrict__ gout) {
  __shared__ _Float16 sAh[128][40], sAl[128][40];
  __shared__ _Float16 sBh[64][40],  sBl[64][40];
  const int tid  = threadIdx.x;
  const int lane = tid & 63;
  const int w    = tid >> 6;
  const int wr   = w >> 1, wc = w & 1;
  const int rm   = blockIdx.x * 128;
  const int cn   = blockIdx.y * 64;
  const int khead = (cn < 512) ? 0 : 128;
  const int lr   = lane & 15, kg = (lane >> 4) * 8;

  f32x4 acc[4][2] = {};

  for (int kt = 0; kt < 128; kt += 32) {
#pragma unroll
    for (int j = 0; j < 2; j++) {
      int row = j * 64 + (tid >> 2);
      int k0  = (tid & 3) * 8;
      size_t g = (size_t)(rm + row) * 256 + khead + kt + k0;
      *reinterpret_cast<uint4*>(&sAh[row][k0]) = *reinterpret_cast<const uint4*>(Hhi + g);
      *reinterpret_cast<uint4*>(&sAl[row][k0]) = *reinterpret_cast<const uint4*>(Hlo + g);
    }
    {
      int n  = tid >> 2;
      int k0 = (tid & 3) * 8;
      size_t g = (size_t)(cn + n) * 128 + kt + k0;
      *reinterpret_cast<uint4*>(&sBh[n][k0]) = *reinterpret_cast<const uint4*>(Whi + g);
      *reinterpret_cast<uint4*>(&sBl[n][k0]) = *reinterpret_cast<const uint4*>(Wlo + g);
    }
    __syncthreads();

    half8 ah[4], al[4], bh[2], bl[2];
#pragma unroll
    for (int m = 0; m < 4; m++) {
      ah[m] = *reinterpret_cast<const half8*>(&sAh[wr * 64 + m * 16 + lr][kg]);
      al[m] = *reinterpret_cast<const half8*>(&sAl[wr * 64 + m * 16 + lr][kg]);
    }
#pragma unroll
    for (int n = 0; n < 2; n++) {
      bh[n] = *reinterpret_cast<const half8*>(&sBh[wc * 32 + n * 16 + lr][kg]);
      bl[n] = *reinterpret_cast<const half8*>(&sBl[wc * 32 + n * 16 + lr][kg]);
    }
#pragma unroll
    for (int m = 0; m < 4; m++)
#pragma unroll
      for (int n = 0; n < 2; n++) {
        acc[m][n] = __builtin_amdgcn_mfma_f32_16x16x32_f16(ah[m], bh[n], acc[m][n], 0, 0, 0);
        acc[m][n] = __builtin_amdgcn_mfma_f32_16x16x32_f16(ah[m], bl[n], acc[m][n], 0, 0, 0);
        acc[m][n] = __builtin_amdgcn_mfma_f32_16x16x32_f16(al[m], bh[n], acc[m][n], 0, 0, 0);
      }
    __syncthreads();
  }

  const float PI = 3.14159265358979323846f;
#pragma unroll
  for (int n = 0; n < 2; n++) {
    int colg = cn + wc * 32 + n * 16 + lr;
    bool isz = (colg < 512);
    float bias = isz ? mb2[colg] : gb2[colg - 512];
#pragma unroll
    for (int m = 0; m < 4; m++) {
#pragma unroll
      for (int r = 0; r < 4; r++) {
        int rowg = rm + wr * 64 + m * 16 + (lane >> 4) * 4 + r;
        float v  = acc[m][n][r] + bias;
        if (isz) {
          zbuf[(size_t)rowg * 512 + colg] = PI * tanhf(v);
        } else {
          gout[(size_t)rowg * 512 + (colg - 512)] = 1.0f / (1.0f + expf(-v));
        }
      }
    }
  }
}

// ---------------------------------------------------------------------------
// Sigma recurrence as Mobius (LFT) parallel scan over T (unchanged).
// ---------------------------------------------------------------------------
__global__ __launch_bounds__(64) void k_mob1(
    const float* __restrict__ g, const float* __restrict__ logQ,
    const float* __restrict__ logR, float* __restrict__ Mbuf) {
  const int c  = blockIdx.x * 64 + threadIdx.x;   // channel 0..2047
  const int ts = blockIdx.y;                      // chunk 0..63
  const int b  = c >> 9, hn = c & 511;
  const float Q = expf(logQ[hn]);
  const float R = expf(logR[hn]);
  const unsigned base = (unsigned)b * (unsigned)(Tc * HN) + (unsigned)(ts * 64) * (unsigned)HN + (unsigned)hn;

  float ma = 1.f, mb = 0.f, mc = 0.f, md = 1.f;
  float gv[32];
#pragma unroll 1
  for (int ph = 0; ph < 2; ph++) {
#pragma unroll
    for (int j = 0; j < 32; j++) gv[j] = g[base + (unsigned)(ph * 32 + j) * 512u];
#pragma unroll
    for (int j = 0; j < 32; j++) {
      float re = R * __builtin_amdgcn_rcpf(gv[j] + 1e-4f);
      float t1 = __builtin_fmaf(Q, mc, ma);
      float t2 = __builtin_fmaf(Q, md, mb);
      ma = re * t1;
      mb = re * t2;
      mc = __builtin_fmaf(re, mc, t1);
      md = __builtin_fmaf(re, md, t2);
      if ((j & 3) == 3) {
        float r = __builtin_amdgcn_rcpf(md);
        ma *= r; mb *= r; mc *= r; md *= r;
      }
    }
  }
  f32x4 M; M[0] = ma; M[1] = mb; M[2] = mc; M[3] = md;
  reinterpret_cast<f32x4*>(Mbuf)[ts * 2048 + c] = M;
}

__global__ __launch_bounds__(64) void k_mob2(
    const float* __restrict__ Mbuf, const float* __restrict__ logS0,
    float* __restrict__ sstart) {
  const int c  = blockIdx.x * 64 + threadIdx.x;   // 0..2047
  const int hn = c & 511;
  float s = expf(logS0[hn]);
  const f32x4* M4 = reinterpret_cast<const f32x4*>(Mbuf);
  f32x4 ring[8];
#pragma unroll
  for (int i = 0; i < 8; i++) ring[i] = M4[i * 2048 + c];
#pragma unroll
  for (int ts = 0; ts < 64; ts++) {
    sstart[ts * 2048 + c] = s;
    f32x4 M = ring[ts & 7];
    if (ts + 8 < 64) ring[ts & 7] = M4[(ts + 8) * 2048 + c];
    s = (M[0] * s + M[1]) / (M[2] * s + M[3]);
  }
}

__global__ __launch_bounds__(64) void k_mob3(
    const float* __restrict__ g, const float* __restrict__ logQ,
    const float* __restrict__ logR, const float* __restrict__ sstart,
    float* __restrict__ Kbuf, float* __restrict__ osig) {
  const int c  = blockIdx.x * 64 + threadIdx.x;
  const int ts = blockIdx.y;
  const int b  = c >> 9, hn = c & 511;
  const float Q = expf(logQ[hn]);
  const float R = expf(logR[hn]);
  const unsigned base = (unsigned)b * (unsigned)(Tc * HN) + (unsigned)(ts * 64) * (unsigned)HN + (unsigned)hn;

  float s = sstart[ts * 2048 + c];
  float gv[32];
#pragma unroll 1
  for (int ph = 0; ph < 2; ph++) {
#pragma unroll
    for (int j = 0; j < 32; j++) gv[j] = g[base + (unsigned)(ph * 32 + j) * 512u];
#pragma unroll
    for (int j = 0; j < 32; j++) {
      const unsigned idx = base + (unsigned)(ph * 32 + j) * 512u;
      float re = R * __builtin_amdgcn_rcpf(gv[j] + 1e-4f);
      float sp = s + Q;
      float K  = sp * __builtin_amdgcn_rcpf(sp + re);
      s = K * re;
      Kbuf[idx] = K;        // Kbuf aliases out_theta ([b][t][hn] layout)
      osig[idx] = s;
    }
  }
}

// ---------------------------------------------------------------------------
// Serial theta scan v3 — producer/consumer with a VMEM-free compute wave.
// Block = 448 thr (7 waves) per 64 channels (all lanes share b; hn contiguous).
// Wave 0: pure LDS+VALU — reads {tp,z,K} from ibuf ring, writes theta to obuf
//         (double-buffered). NO global loads/stores, no vmcnt at barriers.
// Waves 1-6: per chunk-iteration k: flush obuf[chunk k-1] to global (rows
//         wv-1+6i, contiguous 256B stores) AND prefetch ibuf[chunk k+1].
// Theta arithmetic BIT-IDENTICAL to rounds 1-4 (absmax 0.0625 preserved).
// Alias (Karr==oth): K range chunk m loaded at iter m-1; theta stored to that
// range at iter m+1 — barrier-separated, safe.
// ---------------------------------------------------------------------------
__global__ __launch_bounds__(448) void k_scan_theta(
    const float* __restrict__ tp, const float* __restrict__ zarr,
    const float* __restrict__ Karr, float* __restrict__ oth) {
  __shared__ float ibuf[2][3][64][64];   // 96 KB  [dbuf][stream][t][ch]
  __shared__ float obuf[2][64][64];      // 32 KB  [dbuf][t][ch]
  const int tid  = threadIdx.x;
  const int lane = tid & 63;
  const int wv   = tid >> 6;            // 0..6
  const int c    = blockIdx.x * 64 + lane;
  const int b    = c >> 9;
  const int hn   = c & 511;
  const unsigned base = (unsigned)b * (unsigned)(Tc * HN) + (unsigned)hn;

  constexpr float INV2PI = 0.15915494309189535f;
  constexpr float TWOPI  = 6.283185307179586f;

  // loader role (wave-uniform)
  const int s = (wv - 1) >> 1;          // 0:tp 1:z 2:K
  const int h = (wv - 1) & 1;           // half of the 64-step chunk
  const float* src = (s == 0) ? tp : (s == 1) ? zarr : Karr;

  float theta = 0.f, tprev = 0.f;

  // prologue: load chunk 0
  if (wv >= 1) {
    float r[32];
    const unsigned tb = (unsigned)(h * 32);
#pragma unroll
    for (int j = 0; j < 32; j++) r[j] = src[base + (tb + (unsigned)j) * 512u];
#pragma unroll
    for (int j = 0; j < 32; j++) ibuf[0][s][h * 32 + j][lane] = r[j];
  }
  __syncthreads();

#pragma unroll 1
  for (int k = 0; k <= 64; k++) {
    if (wv == 0) {
      if (k < 64) {
        // compute chunk k from LDS with P=8 register ring; theta -> obuf
        float rtp[8], rz[8], rK[8];
#pragma unroll
        for (int i = 0; i < 8; i++) {
          rtp[i] = ibuf[k & 1][0][i][lane];
          rz[i]  = ibuf[k & 1][1][i][lane];
          rK[i]  = ibuf[k & 1][2][i][lane];
        }
#pragma unroll
        for (int j = 0; j < 64; j++) {
          float tpv = rtp[j & 7], zv = rz[j & 7], Kv = rK[j & 7];
          if (j + 8 < 64) {
            rtp[j & 7] = ibuf[k & 1][0][j + 8][lane];
            rz[j & 7]  = ibuf[k & 1][1][j + 8][lane];
            rK[j & 7]  = ibuf[k & 1][2][j + 8][lane];
          }
          float inc = tpv - tprev; tprev = tpv;
          float thp = theta + inc;
          float d   = zv - thp;
          float nr  = rintf(d * INV2PI);
          float innov = __builtin_fmaf(-TWOPI, nr, d);
          theta = __builtin_fmaf(Kv, innov, thp);
          obuf[k & 1][j][lane] = theta;
        }
      }
    } else {
      // flush chunk k-1 output (rows wv-1, wv-1+6, ...)
      if (k >= 1) {
        const unsigned tbase = (unsigned)((k - 1) * 64);
        const int r0 = wv - 1;
#pragma unroll
        for (int i = 0; i < 11; i++) {
          int row = r0 + 6 * i;
          if (row < 64) {
            float v = obuf[(k - 1) & 1][row][lane];
            oth[base + (tbase + (unsigned)row) * 512u] = v;
          }
        }
      }
      // prefetch chunk k+1 inputs
      if (k + 1 < 64) {
        float r[32];
        const unsigned tb = (unsigned)((k + 1) * 64 + h * 32);
#pragma unroll
        for (int j = 0; j < 32; j++) r[j] = src[base + (tb + (unsigned)j) * 512u];
#pragma unroll
        for (int j = 0; j < 32; j++) ibuf[(k + 1) & 1][s][h * 32 + j][lane] = r[j];
      }
    }
    __syncthreads();
  }
}

// ---------------------------------------------------------------------------
extern "C" void kernel_launch(void* const* d_in, const int* in_sizes, int n_in,
                              void* d_out, int out_size, void* d_ws, size_t ws_size,
                              hipStream_t stream) {
  const float* theta_path = (const float*)d_in[0];
  const float* X     = (const float*)d_in[1];
  const float* mw1   = (const float*)d_in[2];
  const float* mb1   = (const float*)d_in[3];
  const float* mw2   = (const float*)d_in[4];
  const float* mb2   = (const float*)d_in[5];
  const float* gw1   = (const float*)d_in[6];
  const float* gb1   = (const float*)d_in[7];
  const float* gw2   = (const float*)d_in[8];
  const float* gb2   = (const float*)d_in[9];
  const float* logQ  = (const float*)d_in[10];
  const float* logR  = (const float*)d_in[11];
  const float* logS0 = (const float*)d_in[12];

  const size_t NOUT = (size_t)BT * HN;       // 8,388,608 per output tensor
  float* out_theta = (float*)d_out;
  float* out_sigma = out_theta + NOUT;
  float* out_g     = out_theta + 2 * NOUT;

  // K buffer aliases out_theta (identical [b][t][hn] layout); see scan notes.
  float* Kbuf = out_theta;

  char* ws = (char*)d_ws;
  _Float16* W1Thi = (_Float16*)(ws);                               // 512 KB
  _Float16* W1Tlo = (_Float16*)(ws + (512u << 10));                // 512 KB
  _Float16* W2Thi = (_Float16*)(ws + (1024u << 10));               // 256 KB
  _Float16* W2Tlo = (_Float16*)(ws + (1280u << 10));               // 256 KB
  _Float16* Hhi   = (_Float16*)(ws + (1536u << 10));               // 8 MB
  _Float16* Hlo   = (_Float16*)(ws + (1536u << 10) + (8u << 20));  // 8 MB
  float*    zbuf  = (float*)  (ws + (1536u << 10) + (16u << 20));  // 32 MB
  float*    Mbuf  = (float*)  (ws + (1536u << 10) + (48u << 20));  // 2 MB
  float*    sst   = (float*)  (ws + (1536u << 10) + (50u << 20));  // 512 KB
  // total ws use ~52 MB

  k_split_w<<<1536, 256, 0, stream>>>(mw1, gw1, mw2, gw2, W1Thi, W1Tlo, W2Thi, W2Tlo);
  k_gemm1<<<dim3(128, 4), 256, 0, stream>>>(X, W1Thi, W1Tlo, mb1, gb1, Hhi, Hlo);
  k_gemm2<<<dim3(128, 16), 256, 0, stream>>>(Hhi, Hlo, W2Thi, W2Tlo, mb2, gb2, zbuf, out_g);
  k_mob1<<<dim3(32, 64), 64, 0, stream>>>(out_g, logQ, logR, Mbuf);
  k_mob2<<<32, 64, 0, stream>>>(Mbuf, logS0, sst);
  k_mob3<<<dim3(32, 64), 64, 0, stream>>>(out_g, logQ, logR, sst, Kbuf, out_sigma);
  k_scan_theta<<<32, 448, 0, stream>>>(theta_path, zbuf, Kbuf, out_theta);
}

// Round 6
// 218.229 us; speedup vs baseline: 1.6258x; 1.0155x over previous
//
#include <hip/hip_runtime.h>
#include <cstdint>
#include <cstddef>

typedef _Float16 half8  __attribute__((ext_vector_type(8)));
typedef float    f32x4  __attribute__((ext_vector_type(4)));

constexpr int Bc = 4, Tc = 4096, Hc = 16, NBc = 32, Dc = 1024, HIDc = 128;
constexpr int HN = Hc * NBc;      // 512
constexpr int BT = Bc * Tc;       // 16384

// ---------------------------------------------------------------------------
// split helper: 8 f32 -> f16 hi/lo (3-term split-f16 MFMA precision)
// ---------------------------------------------------------------------------
__device__ inline void split8(const float* __restrict__ p,
                              _Float16* __restrict__ dh,
                              _Float16* __restrict__ dl) {
  float4 a = *reinterpret_cast<const float4*>(p);
  float4 b = *reinterpret_cast<const float4*>(p + 4);
  float v[8] = {a.x, a.y, a.z, a.w, b.x, b.y, b.z, b.w};
  half8 hi, lo;
#pragma unroll
  for (int j = 0; j < 8; j++) {
    _Float16 h = (_Float16)v[j];
    hi[j] = h;
    lo[j] = (_Float16)(v[j] - (float)h);
  }
  *reinterpret_cast<half8*>(dh) = hi;
  *reinterpret_cast<half8*>(dl) = lo;
}

// ---------------------------------------------------------------------------
// Kernel: build transposed f16 hi/lo weights.
// ---------------------------------------------------------------------------
__global__ __launch_bounds__(256) void k_split_w(
    const float* __restrict__ mw1, const float* __restrict__ gw1,
    const float* __restrict__ mw2, const float* __restrict__ gw2,
    _Float16* __restrict__ W1Thi, _Float16* __restrict__ W1Tlo,
    _Float16* __restrict__ W2Thi, _Float16* __restrict__ W2Tlo) {
  unsigned i = blockIdx.x * 256u + threadIdx.x;
  if (i < 262144u) {                                   // W1T: n in [0,256), k in [0,1024)
    unsigned n = i >> 10, k = i & 1023u;
    float v = (n < 128u) ? mw1[k * 128u + n] : gw1[k * 128u + (n - 128u)];
    _Float16 h = (_Float16)v;
    W1Thi[i] = h;
    W1Tlo[i] = (_Float16)(v - (float)h);
  } else {                                             // W2T: j in [0,1024), k in [0,128)
    unsigned j2 = i - 262144u;
    unsigned n = j2 >> 7, k = j2 & 127u;
    float v = (n < 512u) ? mw2[k * 512u + n] : gw2[k * 512u + (n - 512u)];
    _Float16 h = (_Float16)v;
    W2Thi[j2] = h;
    W2Tlo[j2] = (_Float16)(v - (float)h);
  }
}

// ---------------------------------------------------------------------------
// GEMM1: h[16384][256] = gelu(X @ [mw1|gw1] + [mb1|gb1]); split-f16 MFMA.
// ---------------------------------------------------------------------------
__global__ __launch_bounds__(256) void k_gemm1(
    const float* __restrict__ X,
    const _Float16* __restrict__ Whi, const _Float16* __restrict__ Wlo,
    const float* __restrict__ mb1, const float* __restrict__ gb1,
    _Float16* __restrict__ Hhi, _Float16* __restrict__ Hlo) {
  __shared__ _Float16 sAh[128][40], sAl[128][40];   // +8 pad: 80B row stride
  __shared__ _Float16 sBh[64][40],  sBl[64][40];
  const int tid  = threadIdx.x;
  const int lane = tid & 63;
  const int w    = tid >> 6;
  const int wr   = w >> 1, wc = w & 1;
  const int rm   = blockIdx.x * 128;
  const int cn   = blockIdx.y * 64;
  const int lr   = lane & 15, kg = (lane >> 4) * 8;

  f32x4 acc[4][2] = {};

  for (int kt = 0; kt < 1024; kt += 32) {
#pragma unroll
    for (int j = 0; j < 2; j++) {
      int row = j * 64 + (tid >> 2);
      int k0  = (tid & 3) * 8;
      size_t g = (size_t)(rm + row) * 1024 + kt + k0;
      split8(X + g, &sAh[row][k0], &sAl[row][k0]);
    }
    {
      int n  = tid >> 2;
      int k0 = (tid & 3) * 8;
      size_t g = (size_t)(cn + n) * 1024 + kt + k0;
      *reinterpret_cast<uint4*>(&sBh[n][k0]) = *reinterpret_cast<const uint4*>(Whi + g);
      *reinterpret_cast<uint4*>(&sBl[n][k0]) = *reinterpret_cast<const uint4*>(Wlo + g);
    }
    __syncthreads();

    half8 ah[4], al[4], bh[2], bl[2];
#pragma unroll
    for (int m = 0; m < 4; m++) {
      ah[m] = *reinterpret_cast<const half8*>(&sAh[wr * 64 + m * 16 + lr][kg]);
      al[m] = *reinterpret_cast<const half8*>(&sAl[wr * 64 + m * 16 + lr][kg]);
    }
#pragma unroll
    for (int n = 0; n < 2; n++) {
      bh[n] = *reinterpret_cast<const half8*>(&sBh[wc * 32 + n * 16 + lr][kg]);
      bl[n] = *reinterpret_cast<const half8*>(&sBl[wc * 32 + n * 16 + lr][kg]);
    }
#pragma unroll
    for (int m = 0; m < 4; m++)
#pragma unroll
      for (int n = 0; n < 2; n++) {
        acc[m][n] = __builtin_amdgcn_mfma_f32_16x16x32_f16(ah[m], bh[n], acc[m][n], 0, 0, 0);
        acc[m][n] = __builtin_amdgcn_mfma_f32_16x16x32_f16(ah[m], bl[n], acc[m][n], 0, 0, 0);
        acc[m][n] = __builtin_amdgcn_mfma_f32_16x16x32_f16(al[m], bh[n], acc[m][n], 0, 0, 0);
      }
    __syncthreads();
  }

#pragma unroll
  for (int n = 0; n < 2; n++) {
    int colg = cn + wc * 32 + n * 16 + lr;
    float bias = (colg < 128) ? mb1[colg] : gb1[colg - 128];
#pragma unroll
    for (int m = 0; m < 4; m++) {
#pragma unroll
      for (int r = 0; r < 4; r++) {
        int rowg = rm + wr * 64 + m * 16 + (lane >> 4) * 4 + r;
        float v  = acc[m][n][r] + bias;
        float ge = 0.5f * v * (1.0f + erff(v * 0.70710678118654752f));
        _Float16 h = (_Float16)ge;
        Hhi[(size_t)rowg * 256 + colg] = h;
        Hlo[(size_t)rowg * 256 + colg] = (_Float16)(ge - (float)h);
      }
    }
  }
}

// ---------------------------------------------------------------------------
// GEMM2: logits[16384][1024]; cols<512: z = pi*tanh(.)  -> zbuf[row][512]
//                             cols>=512: g = sigmoid(.) -> gout[row][512]
// ---------------------------------------------------------------------------
__global__ __launch_bounds__(256) void k_gemm2(
    const _Float16* __restrict__ Hhi, const _Float16* __restrict__ Hlo,
    const _Float16* __restrict__ Whi, const _Float16* __restrict__ Wlo,
    const float* __restrict__ mb2, const float* __restrict__ gb2,
    float* __restrict__ zbuf, float* __restrict__ gout) {
  __shared__ _Float16 sAh[128][40], sAl[128][40];
  __shared__ _Float16 sBh[64][40],  sBl[64][40];
  const int tid  = threadIdx.x;
  const int lane = tid & 63;
  const int w    = tid >> 6;
  const int wr   = w >> 1, wc = w & 1;
  const int rm   = blockIdx.x * 128;
  const int cn   = blockIdx.y * 64;
  const int khead = (cn < 512) ? 0 : 128;
  const int lr   = lane & 15, kg = (lane >> 4) * 8;

  f32x4 acc[4][2] = {};

  for (int kt = 0; kt < 128; kt += 32) {
#pragma unroll
    for (int j = 0; j < 2; j++) {
      int row = j * 64 + (tid >> 2);
      int k0  = (tid & 3) * 8;
      size_t g = (size_t)(rm + row) * 256 + khead + kt + k0;
      *reinterpret_cast<uint4*>(&sAh[row][k0]) = *reinterpret_cast<const uint4*>(Hhi + g);
      *reinterpret_cast<uint4*>(&sAl[row][k0]) = *reinterpret_cast<const uint4*>(Hlo + g);
    }
    {
      int n  = tid >> 2;
      int k0 = (tid & 3) * 8;
      size_t g = (size_t)(cn + n) * 128 + kt + k0;
      *reinterpret_cast<uint4*>(&sBh[n][k0]) = *reinterpret_cast<const uint4*>(Whi + g);
      *reinterpret_cast<uint4*>(&sBl[n][k0]) = *reinterpret_cast<const uint4*>(Wlo + g);
    }
    __syncthreads();

    half8 ah[4], al[4], bh[2], bl[2];
#pragma unroll
    for (int m = 0; m < 4; m++) {
      ah[m] = *reinterpret_cast<const half8*>(&sAh[wr * 64 + m * 16 + lr][kg]);
      al[m] = *reinterpret_cast<const half8*>(&sAl[wr * 64 + m * 16 + lr][kg]);
    }
#pragma unroll
    for (int n = 0; n < 2; n++) {
      bh[n] = *reinterpret_cast<const half8*>(&sBh[wc * 32 + n * 16 + lr][kg]);
      bl[n] = *reinterpret_cast<const half8*>(&sBl[wc * 32 + n * 16 + lr][kg]);
    }
#pragma unroll
    for (int m = 0; m < 4; m++)
#pragma unroll
      for (int n = 0; n < 2; n++) {
        acc[m][n] = __builtin_amdgcn_mfma_f32_16x16x32_f16(ah[m], bh[n], acc[m][n], 0, 0, 0);
        acc[m][n] = __builtin_amdgcn_mfma_f32_16x16x32_f16(ah[m], bl[n], acc[m][n], 0, 0, 0);
        acc[m][n] = __builtin_amdgcn_mfma_f32_16x16x32_f16(al[m], bh[n], acc[m][n], 0, 0, 0);
      }
    __syncthreads();
  }

  const float PI = 3.14159265358979323846f;
#pragma unroll
  for (int n = 0; n < 2; n++) {
    int colg = cn + wc * 32 + n * 16 + lr;
    bool isz = (colg < 512);
    float bias = isz ? mb2[colg] : gb2[colg - 512];
#pragma unroll
    for (int m = 0; m < 4; m++) {
#pragma unroll
      for (int r = 0; r < 4; r++) {
        int rowg = rm + wr * 64 + m * 16 + (lane >> 4) * 4 + r;
        float v  = acc[m][n][r] + bias;
        if (isz) {
          zbuf[(size_t)rowg * 512 + colg] = PI * tanhf(v);
        } else {
          gout[(size_t)rowg * 512 + (colg - 512)] = 1.0f / (1.0f + expf(-v));
        }
      }
    }
  }
}

// ---------------------------------------------------------------------------
// Sigma recurrence as Mobius (LFT) parallel scan over T (unchanged).
// ---------------------------------------------------------------------------
__global__ __launch_bounds__(64) void k_mob1(
    const float* __restrict__ g, const float* __restrict__ logQ,
    const float* __restrict__ logR, float* __restrict__ Mbuf) {
  const int c  = blockIdx.x * 64 + threadIdx.x;   // channel 0..2047
  const int ts = blockIdx.y;                      // chunk 0..63
  const int b  = c >> 9, hn = c & 511;
  const float Q = expf(logQ[hn]);
  const float R = expf(logR[hn]);
  const unsigned base = (unsigned)b * (unsigned)(Tc * HN) + (unsigned)(ts * 64) * (unsigned)HN + (unsigned)hn;

  float ma = 1.f, mb = 0.f, mc = 0.f, md = 1.f;
  float gv[32];
#pragma unroll 1
  for (int ph = 0; ph < 2; ph++) {
#pragma unroll
    for (int j = 0; j < 32; j++) gv[j] = g[base + (unsigned)(ph * 32 + j) * 512u];
#pragma unroll
    for (int j = 0; j < 32; j++) {
      float re = R * __builtin_amdgcn_rcpf(gv[j] + 1e-4f);
      float t1 = __builtin_fmaf(Q, mc, ma);
      float t2 = __builtin_fmaf(Q, md, mb);
      ma = re * t1;
      mb = re * t2;
      mc = __builtin_fmaf(re, mc, t1);
      md = __builtin_fmaf(re, md, t2);
      if ((j & 3) == 3) {
        float r = __builtin_amdgcn_rcpf(md);
        ma *= r; mb *= r; mc *= r; md *= r;
      }
    }
  }
  f32x4 M; M[0] = ma; M[1] = mb; M[2] = mc; M[3] = md;
  reinterpret_cast<f32x4*>(Mbuf)[ts * 2048 + c] = M;
}

__global__ __launch_bounds__(64) void k_mob2(
    const float* __restrict__ Mbuf, const float* __restrict__ logS0,
    float* __restrict__ sstart) {
  const int c  = blockIdx.x * 64 + threadIdx.x;   // 0..2047
  const int hn = c & 511;
  float s = expf(logS0[hn]);
  const f32x4* M4 = reinterpret_cast<const f32x4*>(Mbuf);
  f32x4 ring[8];
#pragma unroll
  for (int i = 0; i < 8; i++) ring[i] = M4[i * 2048 + c];
#pragma unroll
  for (int ts = 0; ts < 64; ts++) {
    sstart[ts * 2048 + c] = s;
    f32x4 M = ring[ts & 7];
    if (ts + 8 < 64) ring[ts & 7] = M4[(ts + 8) * 2048 + c];
    s = (M[0] * s + M[1]) / (M[2] * s + M[3]);
  }
}

__global__ __launch_bounds__(64) void k_mob3(
    const float* __restrict__ g, const float* __restrict__ logQ,
    const float* __restrict__ logR, const float* __restrict__ sstart,
    float* __restrict__ Kbuf, float* __restrict__ osig) {
  const int c  = blockIdx.x * 64 + threadIdx.x;
  const int ts = blockIdx.y;
  const int b  = c >> 9, hn = c & 511;
  const float Q = expf(logQ[hn]);
  const float R = expf(logR[hn]);
  const unsigned base = (unsigned)b * (unsigned)(Tc * HN) + (unsigned)(ts * 64) * (unsigned)HN + (unsigned)hn;

  float s = sstart[ts * 2048 + c];
  float gv[32];
#pragma unroll 1
  for (int ph = 0; ph < 2; ph++) {
#pragma unroll
    for (int j = 0; j < 32; j++) gv[j] = g[base + (unsigned)(ph * 32 + j) * 512u];
#pragma unroll
    for (int j = 0; j < 32; j++) {
      const unsigned idx = base + (unsigned)(ph * 32 + j) * 512u;
      float re = R * __builtin_amdgcn_rcpf(gv[j] + 1e-4f);
      float sp = s + Q;
      float K  = sp * __builtin_amdgcn_rcpf(sp + re);
      s = K * re;
      Kbuf[idx] = K;        // Kbuf aliases out_theta ([b][t][hn] layout)
      osig[idx] = s;
    }
  }
}

// ---------------------------------------------------------------------------
// Serial theta scan v4 — VMEM-free compute wave + b128-batched LDS.
// LDS tiles are [ch][t-block] float4 with XOR swizzle (tb ^= ch&15) so
// wave 0 issues ONE ds_read_b128 per stream per 4 steps (1 DS op/step
// total incl. the theta write) -> lgkmcnt lookahead fits in the HW cap.
// Waves 1-6: flush obuf[chunk k-1] (b128 read + coalesced stores) and
// prefetch ibuf[chunk k+1] (strided loads + b128 LDS writes).
// Theta arithmetic BIT-IDENTICAL to rounds 1-5 (absmax 0.0625 preserved).
// Alias (Karr==oth): K chunk m read at iter m-1; theta stored at iter m+1.
// ---------------------------------------------------------------------------
__global__ __launch_bounds__(448) void k_scan_theta(
    const float* __restrict__ tp, const float* __restrict__ zarr,
    const float* __restrict__ Karr, float* __restrict__ oth) {
  __shared__ float4 ibuf[2][3][64][16];   // 96 KB  [dbuf][stream][ch][tblk]
  __shared__ float4 obuf[2][64][16];      // 32 KB  [dbuf][ch][tblk]
  const int tid  = threadIdx.x;
  const int lane = tid & 63;
  const int wv   = tid >> 6;            // 0..6
  const int xo   = lane & 15;           // swizzle key
  const int c    = blockIdx.x * 64 + lane;
  const int b    = c >> 9;
  const int hn   = c & 511;
  const unsigned base = (unsigned)b * (unsigned)(Tc * HN) + (unsigned)hn;

  constexpr float INV2PI = 0.15915494309189535f;
  constexpr float TWOPI  = 6.283185307179586f;

  // loader role (wave-uniform)
  const int s = (wv - 1) >> 1;          // 0:tp 1:z 2:K
  const int h = (wv - 1) & 1;           // half of the 64-step chunk
  const float* src = (s == 0) ? tp : (s == 1) ? zarr : Karr;

  float theta = 0.f, tprev = 0.f;

  // prologue: load chunk 0 inputs
  if (wv >= 1) {
    float r[32];
    const unsigned tb0 = (unsigned)(h * 32);
#pragma unroll
    for (int j = 0; j < 32; j++) r[j] = src[base + (tb0 + (unsigned)j) * 512u];
#pragma unroll
    for (int jj = 0; jj < 8; jj++) {
      float4 v; v.x = r[4*jj]; v.y = r[4*jj+1]; v.z = r[4*jj+2]; v.w = r[4*jj+3];
      ibuf[0][s][lane][(h * 8 + jj) ^ xo] = v;
    }
  }
  __syncthreads();

#pragma unroll 1
  for (int k = 0; k <= 64; k++) {
    if (wv == 0) {
      if (k < 64) {
        const int db = k & 1;
        float4 rg[3][3];                 // [slot][stream], slot = blk%3
        // issue blocks 0,1
#pragma unroll
        for (int sl = 0; sl < 2; sl++) {
#pragma unroll
          for (int st = 0; st < 3; st++) rg[sl][st] = ibuf[db][st][lane][sl ^ xo];
        }
#pragma unroll
        for (int m = 0; m < 16; m++) {
          // prefetch block m+2 (2-block lookahead > LDS latency)
          if (m + 2 < 16) {
#pragma unroll
            for (int st = 0; st < 3; st++)
              rg[(m + 2) % 3][st] = ibuf[db][st][lane][(m + 2) ^ xo];
          }
          float4 t4 = rg[m % 3][0];
          float4 z4 = rg[m % 3][1];
          float4 K4 = rg[m % 3][2];
          float4 th;
#pragma unroll
          for (int j = 0; j < 4; j++) {
            float tpv = (j == 0) ? t4.x : (j == 1) ? t4.y : (j == 2) ? t4.z : t4.w;
            float zv  = (j == 0) ? z4.x : (j == 1) ? z4.y : (j == 2) ? z4.z : z4.w;
            float Kv  = (j == 0) ? K4.x : (j == 1) ? K4.y : (j == 2) ? K4.z : K4.w;
            float inc = tpv - tprev; tprev = tpv;
            float thp = theta + inc;
            float d   = zv - thp;
            float nr  = rintf(d * INV2PI);
            float innov = __builtin_fmaf(-TWOPI, nr, d);
            theta = __builtin_fmaf(Kv, innov, thp);
            if (j == 0) th.x = theta; else if (j == 1) th.y = theta;
            else if (j == 2) th.z = theta; else th.w = theta;
          }
          obuf[db][lane][m ^ xo] = th;
        }
      }
    } else {
      // flush chunk k-1 output: blocks tb = wv-1, wv-1+6, wv-1+12 (<16)
      if (k >= 1) {
        const unsigned tbase = (unsigned)((k - 1) * 64);
        const int fdb = (k - 1) & 1;
#pragma unroll
        for (int i = 0; i < 3; i++) {
          int tb = (wv - 1) + 6 * i;
          if (tb < 16) {
            float4 v = obuf[fdb][lane][tb ^ xo];
            oth[base + (tbase + (unsigned)(4 * tb)    ) * 512u] = v.x;
            oth[base + (tbase + (unsigned)(4 * tb + 1)) * 512u] = v.y;
            oth[base + (tbase + (unsigned)(4 * tb + 2)) * 512u] = v.z;
            oth[base + (tbase + (unsigned)(4 * tb + 3)) * 512u] = v.w;
          }
        }
      }
      // prefetch chunk k+1 inputs
      if (k + 1 < 64) {
        float r[32];
        const unsigned tb0 = (unsigned)((k + 1) * 64 + h * 32);
#pragma unroll
        for (int j = 0; j < 32; j++) r[j] = src[base + (tb0 + (unsigned)j) * 512u];
        const int pdb = (k + 1) & 1;
#pragma unroll
        for (int jj = 0; jj < 8; jj++) {
          float4 v; v.x = r[4*jj]; v.y = r[4*jj+1]; v.z = r[4*jj+2]; v.w = r[4*jj+3];
          ibuf[pdb][s][lane][(h * 8 + jj) ^ xo] = v;
        }
      }
    }
    __syncthreads();
  }
}

// ---------------------------------------------------------------------------
extern "C" void kernel_launch(void* const* d_in, const int* in_sizes, int n_in,
                              void* d_out, int out_size, void* d_ws, size_t ws_size,
                              hipStream_t stream) {
  const float* theta_path = (const float*)d_in[0];
  const float* X     = (const float*)d_in[1];
  const float* mw1   = (const float*)d_in[2];
  const float* mb1   = (const float*)d_in[3];
  const float* mw2   = (const float*)d_in[4];
  const float* mb2   = (const float*)d_in[5];
  const float* gw1   = (const float*)d_in[6];
  const float* gb1   = (const float*)d_in[7];
  const float* gw2   = (const float*)d_in[8];
  const float* gb2   = (const float*)d_in[9];
  const float* logQ  = (const float*)d_in[10];
  const float* logR  = (const float*)d_in[11];
  const float* logS0 = (const float*)d_in[12];

  const size_t NOUT = (size_t)BT * HN;       // 8,388,608 per output tensor
  float* out_theta = (float*)d_out;
  float* out_sigma = out_theta + NOUT;
  float* out_g     = out_theta + 2 * NOUT;

  // K buffer aliases out_theta (identical [b][t][hn] layout); see scan notes.
  float* Kbuf = out_theta;

  char* ws = (char*)d_ws;
  _Float16* W1Thi = (_Float16*)(ws);                               // 512 KB
  _Float16* W1Tlo = (_Float16*)(ws + (512u << 10));                // 512 KB
  _Float16* W2Thi = (_Float16*)(ws + (1024u << 10));               // 256 KB
  _Float16* W2Tlo = (_Float16*)(ws + (1280u << 10));               // 256 KB
  _Float16* Hhi   = (_Float16*)(ws + (1536u << 10));               // 8 MB
  _Float16* Hlo   = (_Float16*)(ws + (1536u << 10) + (8u << 20));  // 8 MB
  float*    zbuf  = (float*)  (ws + (1536u << 10) + (16u << 20));  // 32 MB
  float*    Mbuf  = (float*)  (ws + (1536u << 10) + (48u << 20));  // 2 MB
  float*    sst   = (float*)  (ws + (1536u << 10) + (50u << 20));  // 512 KB
  // total ws use ~52 MB

  k_split_w<<<1536, 256, 0, stream>>>(mw1, gw1, mw2, gw2, W1Thi, W1Tlo, W2Thi, W2Tlo);
  k_gemm1<<<dim3(128, 4), 256, 0, stream>>>(X, W1Thi, W1Tlo, mb1, gb1, Hhi, Hlo);
  k_gemm2<<<dim3(128, 16), 256, 0, stream>>>(Hhi, Hlo, W2Thi, W2Tlo, mb2, gb2, zbuf, out_g);
  k_mob1<<<dim3(32, 64), 64, 0, stream>>>(out_g, logQ, logR, Mbuf);
  k_mob2<<<32, 64, 0, stream>>>(Mbuf, logS0, sst);
  k_mob3<<<dim3(32, 64), 64, 0, stream>>>(out_g, logQ, logR, sst, Kbuf, out_sigma);
  k_scan_theta<<<32, 448, 0, stream>>>(theta_path, zbuf, Kbuf, out_theta);
}

// Round 7
// 192.107 us; speedup vs baseline: 1.8469x; 1.1360x over previous
//
#include <hip/hip_runtime.h>
#include <cstdint>
#include <cstddef>

typedef _Float16 half8  __attribute__((ext_vector_type(8)));
typedef float    f32x4  __attribute__((ext_vector_type(4)));

constexpr int Bc = 4, Tc = 4096, Hc = 16, NBc = 32, Dc = 1024, HIDc = 128;
constexpr int HN = Hc * NBc;      // 512
constexpr int BT = Bc * Tc;       // 16384

// ---------------------------------------------------------------------------
// split helper: 8 f32 -> f16 hi/lo (3-term split-f16 MFMA precision)
// ---------------------------------------------------------------------------
__device__ inline void split8(const float* __restrict__ p,
                              _Float16* __restrict__ dh,
                              _Float16* __restrict__ dl) {
  float4 a = *reinterpret_cast<const float4*>(p);
  float4 b = *reinterpret_cast<const float4*>(p + 4);
  float v[8] = {a.x, a.y, a.z, a.w, b.x, b.y, b.z, b.w};
  half8 hi, lo;
#pragma unroll
  for (int j = 0; j < 8; j++) {
    _Float16 h = (_Float16)v[j];
    hi[j] = h;
    lo[j] = (_Float16)(v[j] - (float)h);
  }
  *reinterpret_cast<half8*>(dh) = hi;
  *reinterpret_cast<half8*>(dl) = lo;
}

// ---------------------------------------------------------------------------
// Kernel: build transposed f16 hi/lo weights.
// ---------------------------------------------------------------------------
__global__ __launch_bounds__(256) void k_split_w(
    const float* __restrict__ mw1, const float* __restrict__ gw1,
    const float* __restrict__ mw2, const float* __restrict__ gw2,
    _Float16* __restrict__ W1Thi, _Float16* __restrict__ W1Tlo,
    _Float16* __restrict__ W2Thi, _Float16* __restrict__ W2Tlo) {
  unsigned i = blockIdx.x * 256u + threadIdx.x;
  if (i < 262144u) {                                   // W1T: n in [0,256), k in [0,1024)
    unsigned n = i >> 10, k = i & 1023u;
    float v = (n < 128u) ? mw1[k * 128u + n] : gw1[k * 128u + (n - 128u)];
    _Float16 h = (_Float16)v;
    W1Thi[i] = h;
    W1Tlo[i] = (_Float16)(v - (float)h);
  } else {                                             // W2T: j in [0,1024), k in [0,128)
    unsigned j2 = i - 262144u;
    unsigned n = j2 >> 7, k = j2 & 127u;
    float v = (n < 512u) ? mw2[k * 512u + n] : gw2[k * 512u + (n - 512u)];
    _Float16 h = (_Float16)v;
    W2Thi[j2] = h;
    W2Tlo[j2] = (_Float16)(v - (float)h);
  }
}

// ---------------------------------------------------------------------------
// GEMM1: h[16384][256] = gelu(X @ [mw1|gw1] + [mb1|gb1]); split-f16 MFMA.
// ---------------------------------------------------------------------------
__global__ __launch_bounds__(256) void k_gemm1(
    const float* __restrict__ X,
    const _Float16* __restrict__ Whi, const _Float16* __restrict__ Wlo,
    const float* __restrict__ mb1, const float* __restrict__ gb1,
    _Float16* __restrict__ Hhi, _Float16* __restrict__ Hlo) {
  __shared__ _Float16 sAh[128][40], sAl[128][40];   // +8 pad: 80B row stride
  __shared__ _Float16 sBh[64][40],  sBl[64][40];
  const int tid  = threadIdx.x;
  const int lane = tid & 63;
  const int w    = tid >> 6;
  const int wr   = w >> 1, wc = w & 1;
  const int rm   = blockIdx.x * 128;
  const int cn   = blockIdx.y * 64;
  const int lr   = lane & 15, kg = (lane >> 4) * 8;

  f32x4 acc[4][2] = {};

  for (int kt = 0; kt < 1024; kt += 32) {
#pragma unroll
    for (int j = 0; j < 2; j++) {
      int row = j * 64 + (tid >> 2);
      int k0  = (tid & 3) * 8;
      size_t g = (size_t)(rm + row) * 1024 + kt + k0;
      split8(X + g, &sAh[row][k0], &sAl[row][k0]);
    }
    {
      int n  = tid >> 2;
      int k0 = (tid & 3) * 8;
      size_t g = (size_t)(cn + n) * 1024 + kt + k0;
      *reinterpret_cast<uint4*>(&sBh[n][k0]) = *reinterpret_cast<const uint4*>(Whi + g);
      *reinterpret_cast<uint4*>(&sBl[n][k0]) = *reinterpret_cast<const uint4*>(Wlo + g);
    }
    __syncthreads();

    half8 ah[4], al[4], bh[2], bl[2];
#pragma unroll
    for (int m = 0; m < 4; m++) {
      ah[m] = *reinterpret_cast<const half8*>(&sAh[wr * 64 + m * 16 + lr][kg]);
      al[m] = *reinterpret_cast<const half8*>(&sAl[wr * 64 + m * 16 + lr][kg]);
    }
#pragma unroll
    for (int n = 0; n < 2; n++) {
      bh[n] = *reinterpret_cast<const half8*>(&sBh[wc * 32 + n * 16 + lr][kg]);
      bl[n] = *reinterpret_cast<const half8*>(&sBl[wc * 32 + n * 16 + lr][kg]);
    }
#pragma unroll
    for (int m = 0; m < 4; m++)
#pragma unroll
      for (int n = 0; n < 2; n++) {
        acc[m][n] = __builtin_amdgcn_mfma_f32_16x16x32_f16(ah[m], bh[n], acc[m][n], 0, 0, 0);
        acc[m][n] = __builtin_amdgcn_mfma_f32_16x16x32_f16(ah[m], bl[n], acc[m][n], 0, 0, 0);
        acc[m][n] = __builtin_amdgcn_mfma_f32_16x16x32_f16(al[m], bh[n], acc[m][n], 0, 0, 0);
      }
    __syncthreads();
  }

#pragma unroll
  for (int n = 0; n < 2; n++) {
    int colg = cn + wc * 32 + n * 16 + lr;
    float bias = (colg < 128) ? mb1[colg] : gb1[colg - 128];
#pragma unroll
    for (int m = 0; m < 4; m++) {
#pragma unroll
      for (int r = 0; r < 4; r++) {
        int rowg = rm + wr * 64 + m * 16 + (lane >> 4) * 4 + r;
        float v  = acc[m][n][r] + bias;
        float ge = 0.5f * v * (1.0f + erff(v * 0.70710678118654752f));
        _Float16 h = (_Float16)ge;
        Hhi[(size_t)rowg * 256 + colg] = h;
        Hlo[(size_t)rowg * 256 + colg] = (_Float16)(ge - (float)h);
      }
    }
  }
}

// ---------------------------------------------------------------------------
// GEMM2: logits[16384][1024]; cols<512: z = pi*tanh(.)  -> zbuf[row][512]
//                             cols>=512: g = sigmoid(.) -> gout[row][512]
// ---------------------------------------------------------------------------
__global__ __launch_bounds__(256) void k_gemm2(
    const _Float16* __restrict__ Hhi, const _Float16* __restrict__ Hlo,
    const _Float16* __restrict__ Whi, const _Float16* __restrict__ Wlo,
    const float* __restrict__ mb2, const float* __restrict__ gb2,
    float* __restrict__ zbuf, float* __restrict__ gout) {
  __shared__ _Float16 sAh[128][40], sAl[128][40];
  __shared__ _Float16 sBh[64][40],  sBl[64][40];
  const int tid  = threadIdx.x;
  const int lane = tid & 63;
  const int w    = tid >> 6;
  const int wr   = w >> 1, wc = w & 1;
  const int rm   = blockIdx.x * 128;
  const int cn   = blockIdx.y * 64;
  const int khead = (cn < 512) ? 0 : 128;
  const int lr   = lane & 15, kg = (lane >> 4) * 8;

  f32x4 acc[4][2] = {};

  for (int kt = 0; kt < 128; kt += 32) {
#pragma unroll
    for (int j = 0; j < 2; j++) {
      int row = j * 64 + (tid >> 2);
      int k0  = (tid & 3) * 8;
      size_t g = (size_t)(rm + row) * 256 + khead + kt + k0;
      *reinterpret_cast<uint4*>(&sAh[row][k0]) = *reinterpret_cast<const uint4*>(Hhi + g);
      *reinterpret_cast<uint4*>(&sAl[row][k0]) = *reinterpret_cast<const uint4*>(Hlo + g);
    }
    {
      int n  = tid >> 2;
      int k0 = (tid & 3) * 8;
      size_t g = (size_t)(cn + n) * 128 + kt + k0;
      *reinterpret_cast<uint4*>(&sBh[n][k0]) = *reinterpret_cast<const uint4*>(Whi + g);
      *reinterpret_cast<uint4*>(&sBl[n][k0]) = *reinterpret_cast<const uint4*>(Wlo + g);
    }
    __syncthreads();

    half8 ah[4], al[4], bh[2], bl[2];
#pragma unroll
    for (int m = 0; m < 4; m++) {
      ah[m] = *reinterpret_cast<const half8*>(&sAh[wr * 64 + m * 16 + lr][kg]);
      al[m] = *reinterpret_cast<const half8*>(&sAl[wr * 64 + m * 16 + lr][kg]);
    }
#pragma unroll
    for (int n = 0; n < 2; n++) {
      bh[n] = *reinterpret_cast<const half8*>(&sBh[wc * 32 + n * 16 + lr][kg]);
      bl[n] = *reinterpret_cast<const half8*>(&sBl[wc * 32 + n * 16 + lr][kg]);
    }
#pragma unroll
    for (int m = 0; m < 4; m++)
#pragma unroll
      for (int n = 0; n < 2; n++) {
        acc[m][n] = __builtin_amdgcn_mfma_f32_16x16x32_f16(ah[m], bh[n], acc[m][n], 0, 0, 0);
        acc[m][n] = __builtin_amdgcn_mfma_f32_16x16x32_f16(ah[m], bl[n], acc[m][n], 0, 0, 0);
        acc[m][n] = __builtin_amdgcn_mfma_f32_16x16x32_f16(al[m], bh[n], acc[m][n], 0, 0, 0);
      }
    __syncthreads();
  }

  const float PI = 3.14159265358979323846f;
#pragma unroll
  for (int n = 0; n < 2; n++) {
    int colg = cn + wc * 32 + n * 16 + lr;
    bool isz = (colg < 512);
    float bias = isz ? mb2[colg] : gb2[colg - 512];
#pragma unroll
    for (int m = 0; m < 4; m++) {
#pragma unroll
      for (int r = 0; r < 4; r++) {
        int rowg = rm + wr * 64 + m * 16 + (lane >> 4) * 4 + r;
        float v  = acc[m][n][r] + bias;
        if (isz) {
          zbuf[(size_t)rowg * 512 + colg] = PI * tanhf(v);
        } else {
          gout[(size_t)rowg * 512 + (colg - 512)] = 1.0f / (1.0f + expf(-v));
        }
      }
    }
  }
}

// ---------------------------------------------------------------------------
// Sigma recurrence as Mobius (LFT) parallel scan over T (unchanged).
// ---------------------------------------------------------------------------
__global__ __launch_bounds__(64) void k_mob1(
    const float* __restrict__ g, const float* __restrict__ logQ,
    const float* __restrict__ logR, float* __restrict__ Mbuf) {
  const int c  = blockIdx.x * 64 + threadIdx.x;   // channel 0..2047
  const int ts = blockIdx.y;                      // chunk 0..63
  const int b  = c >> 9, hn = c & 511;
  const float Q = expf(logQ[hn]);
  const float R = expf(logR[hn]);
  const unsigned base = (unsigned)b * (unsigned)(Tc * HN) + (unsigned)(ts * 64) * (unsigned)HN + (unsigned)hn;

  float ma = 1.f, mb = 0.f, mc = 0.f, md = 1.f;
  float gv[32];
#pragma unroll 1
  for (int ph = 0; ph < 2; ph++) {
#pragma unroll
    for (int j = 0; j < 32; j++) gv[j] = g[base + (unsigned)(ph * 32 + j) * 512u];
#pragma unroll
    for (int j = 0; j < 32; j++) {
      float re = R * __builtin_amdgcn_rcpf(gv[j] + 1e-4f);
      float t1 = __builtin_fmaf(Q, mc, ma);
      float t2 = __builtin_fmaf(Q, md, mb);
      ma = re * t1;
      mb = re * t2;
      mc = __builtin_fmaf(re, mc, t1);
      md = __builtin_fmaf(re, md, t2);
      if ((j & 3) == 3) {
        float r = __builtin_amdgcn_rcpf(md);
        ma *= r; mb *= r; mc *= r; md *= r;
      }
    }
  }
  f32x4 M; M[0] = ma; M[1] = mb; M[2] = mc; M[3] = md;
  reinterpret_cast<f32x4*>(Mbuf)[ts * 2048 + c] = M;
}

__global__ __launch_bounds__(64) void k_mob2(
    const float* __restrict__ Mbuf, const float* __restrict__ logS0,
    float* __restrict__ sstart) {
  const int c  = blockIdx.x * 64 + threadIdx.x;   // 0..2047
  const int hn = c & 511;
  float s = expf(logS0[hn]);
  const f32x4* M4 = reinterpret_cast<const f32x4*>(Mbuf);
  f32x4 ring[8];
#pragma unroll
  for (int i = 0; i < 8; i++) ring[i] = M4[i * 2048 + c];
#pragma unroll
  for (int ts = 0; ts < 64; ts++) {
    sstart[ts * 2048 + c] = s;
    f32x4 M = ring[ts & 7];
    if (ts + 8 < 64) ring[ts & 7] = M4[(ts + 8) * 2048 + c];
    s = (M[0] * s + M[1]) / (M[2] * s + M[3]);
  }
}

__global__ __launch_bounds__(64) void k_mob3(
    const float* __restrict__ g, const float* __restrict__ logQ,
    const float* __restrict__ logR, const float* __restrict__ sstart,
    float* __restrict__ Kbuf, float* __restrict__ osig) {
  const int c  = blockIdx.x * 64 + threadIdx.x;
  const int ts = blockIdx.y;
  const int b  = c >> 9, hn = c & 511;
  const float Q = expf(logQ[hn]);
  const float R = expf(logR[hn]);
  const unsigned base = (unsigned)b * (unsigned)(Tc * HN) + (unsigned)(ts * 64) * (unsigned)HN + (unsigned)hn;

  float s = sstart[ts * 2048 + c];
  float gv[32];
#pragma unroll 1
  for (int ph = 0; ph < 2; ph++) {
#pragma unroll
    for (int j = 0; j < 32; j++) gv[j] = g[base + (unsigned)(ph * 32 + j) * 512u];
#pragma unroll
    for (int j = 0; j < 32; j++) {
      const unsigned idx = base + (unsigned)(ph * 32 + j) * 512u;
      float re = R * __builtin_amdgcn_rcpf(gv[j] + 1e-4f);
      float sp = s + Q;
      float K  = sp * __builtin_amdgcn_rcpf(sp + re);
      s = K * re;
      Kbuf[idx] = K;        // Kbuf aliases out_theta ([b][t][hn] layout)
      osig[idx] = s;
    }
  }
}

// ---------------------------------------------------------------------------
// Serial theta scan v5 — VMEM-free compute wave, [tblk][ch] LDS layout
// (bank-minimal for b128 with zero per-access VALU, no swizzle), and
// quarter-chunk register double-buffering so ds_read latency is hidden by
// 384 cycles of compute (A/B statically named — no dynamic reg indexing).
// Waves 1-6: flush obuf[chunk k-1] + prefetch ibuf[chunk k+1] as before.
// Theta arithmetic BIT-IDENTICAL to rounds 1-6 (absmax 0.0625 preserved).
// Alias (Karr==oth): K chunk m read at iter m-1; theta stored at iter m+1.
// ---------------------------------------------------------------------------
__global__ __launch_bounds__(448) void k_scan_theta(
    const float* __restrict__ tp, const float* __restrict__ zarr,
    const float* __restrict__ Karr, float* __restrict__ oth) {
  __shared__ float4 ibuf[2][3][16][64];   // 96 KB  [dbuf][stream][tblk][ch]
  __shared__ float4 obuf[2][16][64];      // 32 KB  [dbuf][tblk][ch]
  const int tid  = threadIdx.x;
  const int lane = tid & 63;
  const int wv   = tid >> 6;            // 0..6
  const int c    = blockIdx.x * 64 + lane;
  const int b    = c >> 9;
  const int hn   = c & 511;
  const unsigned base = (unsigned)b * (unsigned)(Tc * HN) + (unsigned)hn;

  constexpr float INV2PI = 0.15915494309189535f;
  constexpr float TWOPI  = 6.283185307179586f;

  // loader role (wave-uniform)
  const int s = (wv - 1) >> 1;          // 0:tp 1:z 2:K
  const int h = (wv - 1) & 1;           // half of the 64-step chunk
  const float* src = (s == 0) ? tp : (s == 1) ? zarr : Karr;

  float theta = 0.f, tprev = 0.f;

  auto load_chunk = [&](int k) {
    float r[32];
    const unsigned tb0 = (unsigned)(k * 64 + h * 32);
#pragma unroll
    for (int j = 0; j < 32; j++) r[j] = src[base + (tb0 + (unsigned)j) * 512u];
#pragma unroll
    for (int jj = 0; jj < 8; jj++) {
      float4 v; v.x = r[4*jj]; v.y = r[4*jj+1]; v.z = r[4*jj+2]; v.w = r[4*jj+3];
      ibuf[k & 1][s][h * 8 + jj][lane] = v;
    }
  };

  // prologue: load chunk 0 inputs
  if (wv >= 1) load_chunk(0);
  __syncthreads();

#pragma unroll 1
  for (int k = 0; k <= 64; k++) {
    if (wv == 0) {
      if (k < 64) {
        const int db = k & 1;
        float4 A[3][4], B[3][4];        // [stream][blk-in-quarter]

        auto LOADQ = [&](float4 (&dst)[3][4], int q) {
#pragma unroll
          for (int m2 = 0; m2 < 4; m2++)
#pragma unroll
            for (int st = 0; st < 3; st++)
              dst[st][m2] = ibuf[db][st][q * 4 + m2][lane];
        };
        auto COMPQ = [&](float4 (&sq)[3][4], int q) {
#pragma unroll
          for (int m2 = 0; m2 < 4; m2++) {
            float4 t4 = sq[0][m2], z4 = sq[1][m2], K4 = sq[2][m2];
            float4 th;
#pragma unroll
            for (int j = 0; j < 4; j++) {
              float tpv = (j == 0) ? t4.x : (j == 1) ? t4.y : (j == 2) ? t4.z : t4.w;
              float zv  = (j == 0) ? z4.x : (j == 1) ? z4.y : (j == 2) ? z4.z : z4.w;
              float Kv  = (j == 0) ? K4.x : (j == 1) ? K4.y : (j == 2) ? K4.z : K4.w;
              float inc = tpv - tprev; tprev = tpv;
              float thp = theta + inc;
              float d   = zv - thp;
              float nr  = rintf(d * INV2PI);
              float innov = __builtin_fmaf(-TWOPI, nr, d);
              theta = __builtin_fmaf(Kv, innov, thp);
              if (j == 0) th.x = theta; else if (j == 1) th.y = theta;
              else if (j == 2) th.z = theta; else th.w = theta;
            }
            obuf[db][q * 4 + m2][lane] = th;
          }
        };

        LOADQ(A, 0);
        LOADQ(B, 1); COMPQ(A, 0);
        LOADQ(A, 2); COMPQ(B, 1);
        LOADQ(B, 3); COMPQ(A, 2);
        COMPQ(B, 3);
      }
    } else {
      // flush chunk k-1 output: blocks tb = wv-1, wv-1+6, wv-1+12 (<16)
      if (k >= 1) {
        const unsigned tbase = (unsigned)((k - 1) * 64);
        const int fdb = (k - 1) & 1;
#pragma unroll
        for (int i = 0; i < 3; i++) {
          int tb = (wv - 1) + 6 * i;
          if (tb < 16) {
            float4 v = obuf[fdb][tb][lane];
            oth[base + (tbase + (unsigned)(4 * tb)    ) * 512u] = v.x;
            oth[base + (tbase + (unsigned)(4 * tb + 1)) * 512u] = v.y;
            oth[base + (tbase + (unsigned)(4 * tb + 2)) * 512u] = v.z;
            oth[base + (tbase + (unsigned)(4 * tb + 3)) * 512u] = v.w;
          }
        }
      }
      // prefetch chunk k+1 inputs
      if (k + 1 < 64) load_chunk(k + 1);
    }
    __syncthreads();
  }
}

// ---------------------------------------------------------------------------
extern "C" void kernel_launch(void* const* d_in, const int* in_sizes, int n_in,
                              void* d_out, int out_size, void* d_ws, size_t ws_size,
                              hipStream_t stream) {
  const float* theta_path = (const float*)d_in[0];
  const float* X     = (const float*)d_in[1];
  const float* mw1   = (const float*)d_in[2];
  const float* mb1   = (const float*)d_in[3];
  const float* mw2   = (const float*)d_in[4];
  const float* mb2   = (const float*)d_in[5];
  const float* gw1   = (const float*)d_in[6];
  const float* gb1   = (const float*)d_in[7];
  const float* gw2   = (const float*)d_in[8];
  const float* gb2   = (const float*)d_in[9];
  const float* logQ  = (const float*)d_in[10];
  const float* logR  = (const float*)d_in[11];
  const float* logS0 = (const float*)d_in[12];

  const size_t NOUT = (size_t)BT * HN;       // 8,388,608 per output tensor
  float* out_theta = (float*)d_out;
  float* out_sigma = out_theta + NOUT;
  float* out_g     = out_theta + 2 * NOUT;

  // K buffer aliases out_theta (identical [b][t][hn] layout); see scan notes.
  float* Kbuf = out_theta;

  char* ws = (char*)d_ws;
  _Float16* W1Thi = (_Float16*)(ws);                               // 512 KB
  _Float16* W1Tlo = (_Float16*)(ws + (512u << 10));                // 512 KB
  _Float16* W2Thi = (_Float16*)(ws + (1024u << 10));               // 256 KB
  _Float16* W2Tlo = (_Float16*)(ws + (1280u << 10));               // 256 KB
  _Float16* Hhi   = (_Float16*)(ws + (1536u << 10));               // 8 MB
  _Float16* Hlo   = (_Float16*)(ws + (1536u << 10) + (8u << 20));  // 8 MB
  float*    zbuf  = (float*)  (ws + (1536u << 10) + (16u << 20));  // 32 MB
  float*    Mbuf  = (float*)  (ws + (1536u << 10) + (48u << 20));  // 2 MB
  float*    sst   = (float*)  (ws + (1536u << 10) + (50u << 20));  // 512 KB
  // total ws use ~52 MB

  k_split_w<<<1536, 256, 0, stream>>>(mw1, gw1, mw2, gw2, W1Thi, W1Tlo, W2Thi, W2Tlo);
  k_gemm1<<<dim3(128, 4), 256, 0, stream>>>(X, W1Thi, W1Tlo, mb1, gb1, Hhi, Hlo);
  k_gemm2<<<dim3(128, 16), 256, 0, stream>>>(Hhi, Hlo, W2Thi, W2Tlo, mb2, gb2, zbuf, out_g);
  k_mob1<<<dim3(32, 64), 64, 0, stream>>>(out_g, logQ, logR, Mbuf);
  k_mob2<<<32, 64, 0, stream>>>(Mbuf, logS0, sst);
  k_mob3<<<dim3(32, 64), 64, 0, stream>>>(out_g, logQ, logR, sst, Kbuf, out_sigma);
  k_scan_theta<<<32, 448, 0, stream>>>(theta_path, zbuf, Kbuf, out_theta);
}